// Round 14
// baseline (2239.823 us; speedup 1.0000x reference)
//
#include <hip/hip_runtime.h>
#include <cmath>

typedef unsigned short u16;
typedef __attribute__((ext_vector_type(8))) short short8;
typedef __attribute__((ext_vector_type(4))) float floatx4;
typedef __attribute__((address_space(3))) unsigned int lds_u32;
typedef const __attribute__((address_space(1))) unsigned int glob_u32;

__device__ __forceinline__ u16 f2bf(float f) {
    unsigned u = __float_as_uint(f);
    unsigned r = u + 0x7fffu + ((u >> 16) & 1u);
    return (u16)(r >> 16);
}
__device__ __forceinline__ float bf2f(u16 h) { return __uint_as_float(((unsigned)h) << 16); }
__device__ __forceinline__ void split2(float x, u16& hi, u16& lo) {
    hi = f2bf(x);
    lo = f2bf(x - bf2f(hi));
}
__device__ __forceinline__ float sigm(float x) {
    x = fminf(fmaxf(x, -30.f), 30.f);
    return 1.0f / (1.0f + __expf(-x));
}
__device__ __forceinline__ float ftanh(float x) {
    x = fminf(fmaxf(x, -15.f), 15.f);
    float e = __expf(2.f * x);
    return (e - 1.f) / (e + 1.f);
}
__device__ __forceinline__ void gload16(const void* g, void* l) {
    __builtin_amdgcn_global_load_lds((glob_u32*)g, (lds_u32*)l, 16, 0, 0);
}

// ---------------- f32 -> bf16 (single) ----------------
__global__ __launch_bounds__(256) void k_cvt(const float* __restrict__ s, u16* __restrict__ d, int n4) {
    int i = blockIdx.x * 256 + threadIdx.x;
    int stride = gridDim.x * 256;
    for (; i < n4; i += stride) {
        float4 v = ((const float4*)s)[i];
        ushort4 o;
        o.x = f2bf(v.x); o.y = f2bf(v.y); o.z = f2bf(v.z); o.w = f2bf(v.w);
        ((ushort4*)d)[i] = o;
    }
}

// att_feats rows (skip row 0 per b) -> bf16 copy
__global__ __launch_bounds__(256) void k_cvt_att(const float* __restrict__ enc, u16* __restrict__ dst) {
    int m = blockIdx.x, b = blockIdx.y, tid = threadIdx.x;
    const float* src = enc + ((size_t)b * 129 + 1 + m) * 1024;
    float4 v = *(const float4*)(src + tid * 4);
    ushort4 o;
    o.x = f2bf(v.x); o.y = f2bf(v.y); o.z = f2bf(v.z); o.w = f2bf(v.w);
    *(ushort4*)(dst + ((size_t)b * 128 + m) * 1024 + tid * 4) = o;
}

// ---------------- f32 -> (hi, lo) bf16 planes ----------------
__global__ __launch_bounds__(256) void k_splitp(const float* __restrict__ s, u16* __restrict__ hi,
                                                u16* __restrict__ lo, int n4) {
    int i = blockIdx.x * 256 + threadIdx.x;
    int stride = gridDim.x * 256;
    for (; i < n4; i += stride) {
        float4 v = ((const float4*)s)[i];
        ushort4 h, l;
        split2(v.x, h.x, l.x); split2(v.y, h.y, l.y);
        split2(v.z, h.z, l.z); split2(v.w, h.w, l.w);
        ((ushort4*)hi)[i] = h;
        ((ushort4*)lo)[i] = l;
    }
}

// ---------------- weight concat builders (hi/lo planes) ----------------
// W1cat (4096 x 2048): [Wih1[:, :1024] | Whh1]
__global__ __launch_bounds__(256) void k_build_w1cat(const float* __restrict__ Wih1, const float* __restrict__ Whh1,
                                                     u16* __restrict__ dh, u16* __restrict__ dl) {
    int row = blockIdx.x;
    int c = threadIdx.x * 8;
    const float* src = (c < 1024) ? (Wih1 + (size_t)row * 3072 + c) : (Whh1 + (size_t)row * 1024 + (c - 1024));
    short8 h, l;
#pragma unroll
    for (int j = 0; j < 8; ++j) { u16 hh, ll; split2(src[j], hh, ll); h[j] = (short)hh; l[j] = (short)ll; }
    *(short8*)(dh + (size_t)row * 2048 + c) = h;
    *(short8*)(dl + (size_t)row * 2048 + c) = l;
}

// Wcat2 (4096 x 3072): [Wih2 | Whh2]   (384 threads)
__global__ __launch_bounds__(384) void k_build_wcat2(const float* __restrict__ Wih2, const float* __restrict__ Whh2,
                                                     u16* __restrict__ dh, u16* __restrict__ dl) {
    int row = blockIdx.x;
    int c = threadIdx.x * 8;
    const float* src = (c < 2048) ? (Wih2 + (size_t)row * 2048 + c) : (Whh2 + (size_t)row * 1024 + (c - 2048));
    short8 h, l;
#pragma unroll
    for (int j = 0; j < 8; ++j) { u16 hh, ll; split2(src[j], hh, ll); h[j] = (short)hh; l[j] = (short)ll; }
    *(short8*)(dh + (size_t)row * 3072 + c) = h;
    *(short8*)(dl + (size_t)row * 3072 + c) = l;
}

// Wx1 (4096 x 2048) = Wih1[:, 1024:3072]
__global__ __launch_bounds__(256) void k_build_wx1(const float* __restrict__ Wih1, u16* __restrict__ dh,
                                                   u16* __restrict__ dl) {
    int row = blockIdx.x;
    int c = threadIdx.x * 8;
    const float* src = Wih1 + (size_t)row * 3072 + 1024 + c;
    short8 h, l;
#pragma unroll
    for (int j = 0; j < 8; ++j) { u16 hh, ll; split2(src[j], hh, ll); h[j] = (short)hh; l[j] = (short)ll; }
    *(short8*)(dh + (size_t)row * 2048 + c) = h;
    *(short8*)(dl + (size_t)row * 2048 + c) = l;
}

// Xaug (1344 x 2048): [gv | x_t] hi/lo
__global__ __launch_bounds__(256) void k_build_xaug(const float* __restrict__ enc, const int* __restrict__ obj,
                                                    const float* __restrict__ bos_w, u16* __restrict__ dh,
                                                    u16* __restrict__ dl) {
    int b = blockIdx.x, t = blockIdx.y, tid = threadIdx.x;
    const float* gv = enc + (size_t)b * 129 * 1024;
    const float* xr;
    if (t == 0) xr = bos_w;
    else {
        int idx = obj[b * 20 + (t - 1)];
        idx = min(max(idx, 0), 127);
        xr = enc + ((size_t)b * 129 + 1 + idx) * 1024;
    }
    size_t rowoff = ((size_t)b * 21 + t) * 2048;
    float4 v0 = *(const float4*)(gv + tid * 4);
    float4 v1 = *(const float4*)(xr + tid * 4);
    ushort4 h0, l0, h1, l1;
    split2(v0.x, h0.x, l0.x); split2(v0.y, h0.y, l0.y); split2(v0.z, h0.z, l0.z); split2(v0.w, h0.w, l0.w);
    split2(v1.x, h1.x, l1.x); split2(v1.y, h1.y, l1.y); split2(v1.z, h1.z, l1.z); split2(v1.w, h1.w, l1.w);
    *(ushort4*)(dh + rowoff + tid * 4) = h0;
    *(ushort4*)(dl + rowoff + tid * 4) = l0;
    *(ushort4*)(dh + rowoff + 1024 + tid * 4) = h1;
    *(ushort4*)(dl + rowoff + 1024 + tid * 4) = l1;
}

// ---------------- MFMA GEMM: C = A @ W^T + b1 + b2, split-precision passes ----------------
template <int APASS, int BPASS, int AREMAP, bool BF16OUT>
__global__ __launch_bounds__(256)
void k_gemm3(const u16* __restrict__ Ah, const u16* __restrict__ Al, int lda,
             const u16* __restrict__ Wh, const u16* __restrict__ Wl, int ldw,
             const float* __restrict__ b1, const float* __restrict__ b2,
             void* __restrict__ Cout, int ldc, int Mrows, int K) {
    constexpr int NP = APASS + BPASS;
    __shared__ char lds[2][NP][8192];
    const int tid = threadIdx.x;
    const int lane = tid & 63;
    const int lr = lane & 15, lk = lane >> 4;
    const int m0 = blockIdx.y * 128, n0 = blockIdx.x * 128;
    const int wid = tid >> 6;
    const int wr = wid >> 1, wc = wid & 1;
    const int wbyte = (tid & 192) * 16;

    floatx4 acc[4][4] = {};
    const int nt = K >> 5;

    auto stage = [&](int bb, int kt) {
        int k0 = kt * 32;
#pragma unroll
        for (int i = 0; i < 2; ++i) {
            int p = i * 256 + tid;
            int s = p ^ ((p >> 2) & 3);
            int row = s >> 2, kc = s & 3;
            size_t aoff;
            int gm = m0 + row;
            if (AREMAP == 1) aoff = (((size_t)(gm >> 7)) * 129 + 1 + (gm & 127)) * 1024 + k0 + kc * 8;
            else {
                int cm = gm < Mrows ? gm : Mrows - 1;
                aoff = (size_t)cm * lda + k0 + kc * 8;
            }
            gload16(Ah + aoff, &lds[bb][0][i * 4096 + wbyte]);
            if constexpr (APASS == 2) gload16(Al + aoff, &lds[bb][1][i * 4096 + wbyte]);
            size_t woff = (size_t)(n0 + row) * ldw + k0 + kc * 8;
            gload16(Wh + woff, &lds[bb][APASS][i * 4096 + wbyte]);
            if constexpr (BPASS == 2) gload16(Wl + woff, &lds[bb][APASS + 1][i * 4096 + wbyte]);
        }
    };

    stage(0, 0);
    __syncthreads();
    for (int t = 0; t < nt; ++t) {
        int bb = t & 1;
        if (t + 1 < nt) stage(bb ^ 1, t + 1);
        short8 ah_[4], al_[4], bh_[4], bl_[4];
#pragma unroll
        for (int mi = 0; mi < 4; ++mi) {
            int row = wr * 64 + mi * 16 + lr;
            int slot = (row * 4 + (lk ^ (row & 3))) * 16;
            ah_[mi] = *(const short8*)&lds[bb][0][slot];
            if constexpr (APASS == 2) al_[mi] = *(const short8*)&lds[bb][1][slot];
        }
#pragma unroll
        for (int ni = 0; ni < 4; ++ni) {
            int row = wc * 64 + ni * 16 + lr;
            int slot = (row * 4 + (lk ^ (row & 3))) * 16;
            bh_[ni] = *(const short8*)&lds[bb][APASS][slot];
            if constexpr (BPASS == 2) bl_[ni] = *(const short8*)&lds[bb][APASS + 1][slot];
        }
#pragma unroll
        for (int mi = 0; mi < 4; ++mi)
#pragma unroll
            for (int ni = 0; ni < 4; ++ni) {
                acc[mi][ni] = __builtin_amdgcn_mfma_f32_16x16x32_bf16(ah_[mi], bh_[ni], acc[mi][ni], 0, 0, 0);
                if constexpr (BPASS == 2)
                    acc[mi][ni] = __builtin_amdgcn_mfma_f32_16x16x32_bf16(ah_[mi], bl_[ni], acc[mi][ni], 0, 0, 0);
                if constexpr (APASS == 2)
                    acc[mi][ni] = __builtin_amdgcn_mfma_f32_16x16x32_bf16(al_[mi], bh_[ni], acc[mi][ni], 0, 0, 0);
            }
        __syncthreads();
    }
#pragma unroll
    for (int mi = 0; mi < 4; ++mi) {
#pragma unroll
        for (int r = 0; r < 4; ++r) {
            int gm = m0 + wr * 64 + mi * 16 + lk * 4 + r;
            if (AREMAP == 0 && gm >= Mrows) continue;
#pragma unroll
            for (int ni = 0; ni < 4; ++ni) {
                int gn = n0 + wc * 64 + ni * 16 + lr;
                float v = acc[mi][ni][r];
                if (b1) v += b1[gn];
                if (b2) v += b2[gn];
                if (BF16OUT) ((u16*)Cout)[(size_t)gm * ldc + gn] = f2bf(v);
                else ((float*)Cout)[(size_t)gm * ldc + gn] = v;
            }
        }
    }
}

// ---------------- skinny 2-pass GEMM, N-tile 32: P[kp] = X(64 x Klen) @ (Wh+Wl)^T(32 rows) ----------------
__global__ __launch_bounds__(256)
void k_gp2(const u16* __restrict__ Xh, int ldx,
           const u16* __restrict__ Wh, const u16* __restrict__ Wl, int ldw,
           int Klen, float* __restrict__ P, int Ntot) {
    __shared__ char lds[2][8192];  // [Xh 4096 | Wh 2048 | Wl 2048]
    const int tid = threadIdx.x, wid = tid >> 6, lane = tid & 63;
    const int lr = lane & 15, lk = lane >> 4;
    const int n0 = blockIdx.x * 32;
    const int koff = blockIdx.y * Klen;
    floatx4 acc[2] = {};
    const int nt = Klen >> 5;

    const int sX = tid ^ ((tid >> 2) & 3);
    const size_t xoff = (size_t)(sX >> 2) * ldx + (sX & 3) * 8 + koff;
    const int xdst = (tid & 192) * 16;
    const int pw = tid & 127;
    const int sW = pw ^ ((pw >> 2) & 3);
    const size_t woff = (size_t)(n0 + (sW >> 2)) * ldw + (sW & 3) * 8 + koff;
    const u16* Wsrc = (tid < 128) ? Wh : Wl;
    const int wdst = 4096 + (wid >> 1) * 2048 + (wid & 1) * 1024;

    auto stage = [&](int bb, int kt) {
        int k0 = kt * 32;
        gload16(Xh + xoff + k0, &lds[bb][xdst]);
        gload16(Wsrc + woff + k0, &lds[bb][wdst]);
    };

    stage(0, 0);
    __syncthreads();
    for (int t = 0; t < nt; ++t) {
        int bb = t & 1;
        if (t + 1 < nt) stage(bb ^ 1, t + 1);
        int arow = wid * 16 + lr;
        short8 xh = *(const short8*)&lds[bb][(arow * 4 + (lk ^ (arow & 3))) * 16];
#pragma unroll
        for (int ni = 0; ni < 2; ++ni) {
            int r = ni * 16 + lr;
            int slot = (r * 4 + (lk ^ (r & 3))) * 16;
            short8 wh = *(const short8*)&lds[bb][4096 + slot];
            short8 wl = *(const short8*)&lds[bb][6144 + slot];
            acc[ni] = __builtin_amdgcn_mfma_f32_16x16x32_bf16(xh, wh, acc[ni], 0, 0, 0);
            acc[ni] = __builtin_amdgcn_mfma_f32_16x16x32_bf16(xh, wl, acc[ni], 0, 0, 0);
        }
        __syncthreads();
    }
    float* Pb = P + (size_t)blockIdx.y * 64 * Ntot;
#pragma unroll
    for (int ni = 0; ni < 2; ++ni)
#pragma unroll
        for (int r = 0; r < 4; ++r) {
            int b = wid * 16 + lk * 4 + r;
            Pb[(size_t)b * Ntot + n0 + ni * 16 + lr] = acc[ni][r];
        }
}

// ---------------- reduce nP partials + LSTM cell (single-bf16 state outputs) ----------------
__global__ __launch_bounds__(256)
void k_finish(const float* __restrict__ P, int Ntot, int nP, const float* __restrict__ xcf,
              const float* __restrict__ b1, const float* __restrict__ b2,
              float* __restrict__ cst,
              u16* __restrict__ w1, int w1s, u16* __restrict__ w2, int w2s,
              float* __restrict__ outf, u16* __restrict__ oh) {
    int idx = blockIdx.x * 256 + threadIdx.x;  // b*1024 + d
    int b = idx >> 10, d = idx & 1023;
    float g[4];
#pragma unroll
    for (int q = 0; q < 4; ++q) {
        int n = q * 1024 + d;
        float s = 0.f;
        for (int p = 0; p < nP; ++p) s += P[((size_t)p * 64 + b) * Ntot + n];
        if (xcf) s += xcf[(size_t)b * 21 * 4096 + n];
        if (b1) s += b1[n];
        if (b2) s += b2[n];
        g[q] = s;
    }
    float cp = cst[idx];
    float cn = sigm(g[1]) * cp + sigm(g[0]) * ftanh(g[2]);
    float hn = sigm(g[3]) * ftanh(cn);
    cst[idx] = cn;
    u16 hh = f2bf(hn);
    w1[b * w1s + d] = hh;
    w2[b * w2s + d] = hh;
    if (outf) outf[(size_t)b * 21 * 1024 + d] = hn;
    if (oh) oh[(size_t)b * 21 * 1024 + d] = hh;
}

// ---------------- merged attention: scores -> softmax -> weighted sum, one block per b ----------------
__global__ __launch_bounds__(256)
void k_att(const float* __restrict__ PAH, const float* __restrict__ bah,
           const float* __restrict__ wa, const float* __restrict__ ba,
           const u16* __restrict__ Patt, const int* __restrict__ amask,
           const u16* __restrict__ attf, u16* __restrict__ X2att) {
    int b = blockIdx.x, tid = threadIdx.x;
    __shared__ float sah[1024], swa[1024];
    __shared__ float sSC[128];
    __shared__ float sred[8];
    int wv = tid >> 6, lane = tid & 63;

    // phase 1: ah vector + wa into LDS
    {
        int d = tid * 4;
        *(float4*)&swa[d] = *(const float4*)(wa + d);
        float4 s;
        float* sp = &s.x;
#pragma unroll
        for (int j = 0; j < 4; ++j) {
            float acc = bah[d + j];
#pragma unroll
            for (int p = 0; p < 4; ++p) acc += PAH[((size_t)p * 64 + b) * 1024 + d + j];
            sp[j] = acc;
        }
        *(float4*)&sah[d] = s;
    }
    __syncthreads();

    // phase 2: 128 scores (each wave: 32 m's)
    float bav = ba[0];
    for (int j = 0; j < 32; ++j) {
        int m = wv * 32 + j;
        const u16* pr = Patt + ((size_t)(b * 128 + m)) * 1024;
        float part = 0.f;
#pragma unroll
        for (int c = 0; c < 4; ++c) {
            int d = c * 256 + lane * 4;
            ushort4 p4 = *(const ushort4*)(pr + d);
            float4 a4 = *(const float4*)&sah[d];
            float4 w4 = *(const float4*)&swa[d];
            part += ftanh(bf2f(p4.x) + a4.x) * w4.x + ftanh(bf2f(p4.y) + a4.y) * w4.y +
                    ftanh(bf2f(p4.z) + a4.z) * w4.z + ftanh(bf2f(p4.w) + a4.w) * w4.w;
        }
#pragma unroll
        for (int off = 32; off; off >>= 1) part += __shfl_down(part, off, 64);
        if (lane == 0) {
            float sc = part + bav;
            if (amask[b * 129 + 1 + m] == 0) sc = -1e9f;
            sSC[m] = sc;
        }
    }
    __syncthreads();

    // phase 3: softmax over 128 (in LDS)
    float sv = (tid < 128) ? sSC[tid] : -1e30f;
    float mx = sv;
#pragma unroll
    for (int off = 32; off; off >>= 1) mx = fmaxf(mx, __shfl_down(mx, off, 64));
    if (lane == 0) sred[wv] = mx;
    __syncthreads();
    float gmx = fmaxf(fmaxf(sred[0], sred[1]), fmaxf(sred[2], sred[3]));
    float ev = (tid < 128) ? __expf(sv - gmx) : 0.f;
    float s = ev;
#pragma unroll
    for (int off = 32; off; off >>= 1) s += __shfl_down(s, off, 64);
    if (lane == 0) sred[4 + wv] = s;
    __syncthreads();
    float gsum = sred[4] + sred[5] + sred[6] + sred[7];
    if (tid < 128) sSC[tid] = ev / gsum;   // alpha
    __syncthreads();

    // phase 4: att[d] = sum_m alpha[m] * attf[b,m,d]; each thread 4 d's
    {
        int d = tid * 4;
        const u16* base = attf + (size_t)b * 128 * 1024 + d;
        float4 acc = make_float4(0.f, 0.f, 0.f, 0.f);
#pragma unroll 4
        for (int m = 0; m < 128; ++m) {
            float al = sSC[m];
            ushort4 v = *(const ushort4*)(base + (size_t)m * 1024);
            acc.x += al * bf2f(v.x); acc.y += al * bf2f(v.y);
            acc.z += al * bf2f(v.z); acc.w += al * bf2f(v.w);
        }
        ushort4 o;
        o.x = f2bf(acc.x); o.y = f2bf(acc.y); o.z = f2bf(acc.z); o.w = f2bf(acc.w);
        *(ushort4*)(X2att + (size_t)b * 3072 + d) = o;
    }
}

// ---------------- nce_logit[b,l,j] = ofe[b,l,:] . afe[b,j,:]  (bf16 OFE/AFE, f32 eos) ----------------
__global__ __launch_bounds__(256)
void k_nce_bf(const u16* __restrict__ OFE, const u16* __restrict__ AFE,
              const float* __restrict__ eos_w, float* __restrict__ nce) {
    int l = blockIdx.x, b = blockIdx.y;
    __shared__ u16 sofe[1024];
    int tid = threadIdx.x;
    *(ushort4*)&sofe[tid * 4] = *(const ushort4*)(OFE + ((size_t)b * 21 + l) * 1024 + tid * 4);
    __syncthreads();
    int w = tid >> 6, lane = tid & 63;
    float* outp = nce + ((size_t)b * 21 + l) * 129;
    for (int j = w; j < 129; j += 4) {
        float part = 0.f;
        if (j == 0) {
#pragma unroll
            for (int c = 0; c < 4; ++c) {
                int d = c * 256 + lane * 4;
                float4 a4 = *(const float4*)(eos_w + d);
                ushort4 o4 = *(const ushort4*)&sofe[d];
                part += a4.x * bf2f(o4.x) + a4.y * bf2f(o4.y) + a4.z * bf2f(o4.z) + a4.w * bf2f(o4.w);
            }
        } else {
            const u16* ar = AFE + ((size_t)b * 128 + (j - 1)) * 1024;
#pragma unroll
            for (int c = 0; c < 4; ++c) {
                int d = c * 256 + lane * 4;
                ushort4 a4 = *(const ushort4*)(ar + d);
                ushort4 o4 = *(const ushort4*)&sofe[d];
                part += bf2f(a4.x) * bf2f(o4.x) + bf2f(a4.y) * bf2f(o4.y) +
                        bf2f(a4.z) * bf2f(o4.z) + bf2f(a4.w) * bf2f(o4.w);
            }
        }
#pragma unroll
        for (int off = 32; off; off >>= 1) part += __shfl_down(part, off, 64);
        if (lane == 0) outp[j] = part;
    }
}

extern "C" void kernel_launch(void* const* d_in, const int* in_sizes, int n_in,
                              void* d_out, int out_size, void* d_ws, size_t ws_size,
                              hipStream_t stream) {
    const float* enc  = (const float*)d_in[0];
    const int*   obj  = (const int*)d_in[1];
    const int*   amask= (const int*)d_in[2];
    const float* bosw = (const float*)d_in[3];
    const float* eosw = (const float*)d_in[4];
    const float* Wp   = (const float*)d_in[5];
    const float* bp   = (const float*)d_in[6];
    const float* Wih1 = (const float*)d_in[7];
    const float* Whh1 = (const float*)d_in[8];
    const float* bih1 = (const float*)d_in[9];
    const float* bhh1 = (const float*)d_in[10];
    const float* Wih2 = (const float*)d_in[11];
    const float* Whh2 = (const float*)d_in[12];
    const float* bih2 = (const float*)d_in[13];
    const float* bhh2 = (const float*)d_in[14];
    const float* Wah  = (const float*)d_in[15];
    const float* bah  = (const float*)d_in[16];
    const float* wa   = (const float*)d_in[17];
    const float* ba   = (const float*)d_in[18];
    const float* Wae  = (const float*)d_in[19];
    const float* bae  = (const float*)d_in[20];
    const float* Woe  = (const float*)d_in[21];
    const float* boe  = (const float*)d_in[22];

    float* outputs = (float*)d_out;                    // (64,21,1024)
    float* nce     = outputs + (size_t)64 * 21 * 1024; // (64,21,129)

    char* wp = (char*)d_ws;
    auto alloc = [&](size_t bytes) -> char* { char* p = wp; wp += (bytes + 255) & ~(size_t)255; return p; };
    u16* encbf  = (u16*)alloc((size_t)64 * 129 * 1024 * 2);   // pre-scan only -> scan-state overlay
    u16* Wpbf   = (u16*)alloc((size_t)1024 * 1024 * 2);
    u16* Xaugh  = (u16*)alloc((size_t)1344 * 2048 * 2);       // pre-scan only -> OFEbf overlay
    u16* Xaugl  = (u16*)alloc((size_t)1344 * 2048 * 2);
    u16* W1h    = (u16*)alloc((size_t)4096 * 2048 * 2);
    u16* W1l    = (u16*)alloc((size_t)4096 * 2048 * 2);
    u16* W2h    = (u16*)alloc((size_t)4096 * 3072 * 2);
    u16* W2l    = (u16*)alloc((size_t)4096 * 3072 * 2);
    u16* Wahh   = (u16*)alloc((size_t)1024 * 1024 * 2);
    u16* Wahl   = (u16*)alloc((size_t)1024 * 1024 * 2);
    u16* Waeh   = (u16*)alloc((size_t)1024 * 1024 * 2);
    u16* Wael   = (u16*)alloc((size_t)1024 * 1024 * 2);
    u16* Woeh   = (u16*)alloc((size_t)1024 * 1024 * 2);
    u16* Woel   = (u16*)alloc((size_t)1024 * 1024 * 2);
    // region1: Wx1 hi/lo (33.5MB); after Xc GEMM reused for AFEbf (16.8MB)
    char* region1 = alloc((size_t)2 * 4096 * 2048 * 2);
    u16* Wx1h = (u16*)region1;
    u16* Wx1l = (u16*)region1 + (size_t)4096 * 2048;
    u16* AFEbf = (u16*)region1;
    u16* PattBf  = (u16*)alloc((size_t)8192 * 1024 * 2);
    u16* attfbf  = (u16*)alloc((size_t)64 * 128 * 1024 * 2);
    float* Xcf   = (float*)alloc((size_t)1344 * 4096 * 4);
    u16* Xouth   = (u16*)alloc((size_t)1344 * 1024 * 2);
    float* P2    = (float*)alloc((size_t)4 * 64 * 4096 * 4);
    // OFEbf overlays Xaugh (Xaug dead after Xc GEMM)
    u16* OFEbf = Xaugh;
    // scan-state overlays encbf (encbf dead after pre-scan GEMMs)
    char* sp2 = (char*)encbf;
    auto alloc2 = [&](size_t bytes) -> char* { char* p = sp2; sp2 += (bytes + 255) & ~(size_t)255; return p; };
    float* P1  = (float*)alloc2((size_t)4 * 64 * 4096 * 4);
    float* PAH = (float*)alloc2((size_t)4 * 64 * 1024 * 4);
    u16* XHh   = (u16*)alloc2((size_t)64 * 2048 * 2);   // [h2 | h1]
    u16* X2h   = (u16*)alloc2((size_t)64 * 3072 * 2);   // [att | h1 | h2]
    float* c1  = (float*)alloc2((size_t)64 * 1024 * 4);
    float* c2  = (float*)alloc2((size_t)64 * 1024 * 4);

    dim3 blk(256);
    // prep (encbf region live here; scan-state memsets deferred until after pre-scan GEMMs)
    k_cvt<<<2048, blk, 0, stream>>>(enc, encbf, 64 * 129 * 1024 / 4);
    k_cvt_att<<<dim3(128, 64), blk, 0, stream>>>(enc, attfbf);
    k_cvt<<<1024, blk, 0, stream>>>(Wp, Wpbf, 1024 * 1024 / 4);
    k_splitp<<<1024, blk, 0, stream>>>(Wah, Wahh, Wahl, 1024 * 1024 / 4);
    k_splitp<<<1024, blk, 0, stream>>>(Wae, Waeh, Wael, 1024 * 1024 / 4);
    k_splitp<<<1024, blk, 0, stream>>>(Woe, Woeh, Woel, 1024 * 1024 / 4);
    k_build_wx1<<<4096, blk, 0, stream>>>(Wih1, Wx1h, Wx1l);
    k_build_w1cat<<<4096, blk, 0, stream>>>(Wih1, Whh1, W1h, W1l);
    k_build_wcat2<<<4096, dim3(384), 0, stream>>>(Wih2, Whh2, W2h, W2l);
    k_build_xaug<<<dim3(64, 21), blk, 0, stream>>>(enc, obj, bosw, Xaugh, Xaugl);

    // p_att (bf16 out, single-pass Wp): att_feats @ Wp^T + bp
    k_gemm3<1, 1, 1, true><<<dim3(8, 64), blk, 0, stream>>>(
        encbf, nullptr, 0, Wpbf, nullptr, 1024, bp, nullptr, PattBf, 1024, 8192, 1024);
    // Xc (A+W split, f32 out): Xaug @ Wx1^T + bih1 + bhh1   (reads region1 as Wx1)
    k_gemm3<2, 2, 0, false><<<dim3(32, 11), blk, 0, stream>>>(
        Xaugh, Xaugl, 2048, Wx1h, Wx1l, 2048, bih1, bhh1, Xcf, 4096, 1344, 2048);
    // afe (bf16 out, Wae split): att_feats @ Wae^T + bae   (writes region1 as AFEbf)
    k_gemm3<1, 2, 1, true><<<dim3(8, 64), blk, 0, stream>>>(
        encbf, nullptr, 0, Waeh, Wael, 1024, bae, nullptr, AFEbf, 1024, 8192, 1024);

    // scan-state init (encbf now dead)
    hipMemsetAsync(XHh, 0, (size_t)64 * 2048 * 2, stream);
    hipMemsetAsync(X2h, 0, (size_t)64 * 3072 * 2, stream);
    hipMemsetAsync(c1, 0, (size_t)64 * 1024 * 4, stream);
    hipMemsetAsync(c2, 0, (size_t)64 * 1024 * 4, stream);

    for (int t = 0; t < 21; ++t) {
        // cell1 gates: [h2|h1] @ (W1h+W1l)^T (4096x2048), N-tile 32, K-split 4, 2-pass
        k_gp2<<<dim3(128, 4), blk, 0, stream>>>(XHh, 2048, W1h, W1l, 2048, 512, P1, 4096);
        // LSTM1 finish: + Xc addend (carries biases); h1 -> XH[:,1024:], X2[:,1024:2048]
        k_finish<<<256, blk, 0, stream>>>(P1, 4096, 4, Xcf + (size_t)t * 4096, nullptr, nullptr,
                                          c1, XHh + 1024, 2048, X2h + 1024, 3072, nullptr, nullptr);
        // ah = h1_new @ (Wahh+Wahl)^T, N-tile 32, K-split 4
        k_gp2<<<dim3(32, 4), blk, 0, stream>>>(XHh + 1024, 2048, Wahh, Wahl, 1024, 256, PAH, 1024);
        // merged score+softmax+attsum (one block per b)
        k_att<<<64, blk, 0, stream>>>(PAH, bah, wa, ba, PattBf, amask, attfbf, X2h);
        // cell2 gates: [att|h1|h2] @ (W2h+W2l)^T (4096x3072), N-tile 32, K-split 4, 2-pass
        k_gp2<<<dim3(128, 4), blk, 0, stream>>>(X2h, 3072, W2h, W2l, 3072, 768, P2, 4096);
        // LSTM2 finish: h2 -> XH[:,0:], X2[:,2048:], outputs, Xout
        k_finish<<<256, blk, 0, stream>>>(P2, 4096, 4, nullptr, bih2, bhh2,
                                          c2, XHh, 2048, X2h + 2048, 3072,
                                          outputs + (size_t)t * 1024, Xouth + (size_t)t * 1024);
    }

    // ofe = outputs @ Woe^T + boe (bf16 out; overlays dead Xaug region)
    k_gemm3<1, 2, 0, true><<<dim3(8, 11), blk, 0, stream>>>(
        Xouth, nullptr, 1024, Woeh, Woel, 1024, boe, nullptr, OFEbf, 1024, 1344, 1024);
    k_nce_bf<<<dim3(21, 64), blk, 0, stream>>>(OFEbf, AFEbf, eosw, nce);
}

// Round 15
// 1591.918 us; speedup vs baseline: 1.4070x; 1.4070x over previous
//
#include <hip/hip_runtime.h>
#include <cmath>

typedef unsigned short u16;
typedef __attribute__((ext_vector_type(8))) short short8;
typedef __attribute__((ext_vector_type(4))) float floatx4;
typedef __attribute__((address_space(3))) unsigned int lds_u32;
typedef const __attribute__((address_space(1))) unsigned int glob_u32;

__device__ __forceinline__ u16 f2bf(float f) {
    unsigned u = __float_as_uint(f);
    unsigned r = u + 0x7fffu + ((u >> 16) & 1u);
    return (u16)(r >> 16);
}
__device__ __forceinline__ float bf2f(u16 h) { return __uint_as_float(((unsigned)h) << 16); }
__device__ __forceinline__ void split2(float x, u16& hi, u16& lo) {
    hi = f2bf(x);
    lo = f2bf(x - bf2f(hi));
}
__device__ __forceinline__ float sigm(float x) {
    x = fminf(fmaxf(x, -30.f), 30.f);
    return 1.0f / (1.0f + __expf(-x));
}
__device__ __forceinline__ float ftanh(float x) {
    x = fminf(fmaxf(x, -15.f), 15.f);
    float e = __expf(2.f * x);
    return (e - 1.f) / (e + 1.f);
}
__device__ __forceinline__ void gload16(const void* g, void* l) {
    __builtin_amdgcn_global_load_lds((glob_u32*)g, (lds_u32*)l, 16, 0, 0);
}

// ---------------- f32 -> bf16 (single) ----------------
__global__ __launch_bounds__(256) void k_cvt(const float* __restrict__ s, u16* __restrict__ d, int n4) {
    int i = blockIdx.x * 256 + threadIdx.x;
    int stride = gridDim.x * 256;
    for (; i < n4; i += stride) {
        float4 v = ((const float4*)s)[i];
        ushort4 o;
        o.x = f2bf(v.x); o.y = f2bf(v.y); o.z = f2bf(v.z); o.w = f2bf(v.w);
        ((ushort4*)d)[i] = o;
    }
}

// att_feats rows (skip row 0 per b) -> bf16 copy for attsum
__global__ __launch_bounds__(256) void k_cvt_att(const float* __restrict__ enc, u16* __restrict__ dst) {
    int m = blockIdx.x, b = blockIdx.y, tid = threadIdx.x;
    const float* src = enc + ((size_t)b * 129 + 1 + m) * 1024;
    float4 v = *(const float4*)(src + tid * 4);
    ushort4 o;
    o.x = f2bf(v.x); o.y = f2bf(v.y); o.z = f2bf(v.z); o.w = f2bf(v.w);
    *(ushort4*)(dst + ((size_t)b * 128 + m) * 1024 + tid * 4) = o;
}

// ---------------- f32 -> (hi, lo) bf16 planes ----------------
__global__ __launch_bounds__(256) void k_splitp(const float* __restrict__ s, u16* __restrict__ hi,
                                                u16* __restrict__ lo, int n4) {
    int i = blockIdx.x * 256 + threadIdx.x;
    int stride = gridDim.x * 256;
    for (; i < n4; i += stride) {
        float4 v = ((const float4*)s)[i];
        ushort4 h, l;
        split2(v.x, h.x, l.x); split2(v.y, h.y, l.y);
        split2(v.z, h.z, l.z); split2(v.w, h.w, l.w);
        ((ushort4*)hi)[i] = h;
        ((ushort4*)lo)[i] = l;
    }
}

// ---------------- weight concat builders (hi/lo planes) ----------------
// W1cat (4096 x 2048): [Wih1[:, :1024] | Whh1]
__global__ __launch_bounds__(256) void k_build_w1cat(const float* __restrict__ Wih1, const float* __restrict__ Whh1,
                                                     u16* __restrict__ dh, u16* __restrict__ dl) {
    int row = blockIdx.x;
    int c = threadIdx.x * 8;
    const float* src = (c < 1024) ? (Wih1 + (size_t)row * 3072 + c) : (Whh1 + (size_t)row * 1024 + (c - 1024));
    short8 h, l;
#pragma unroll
    for (int j = 0; j < 8; ++j) { u16 hh, ll; split2(src[j], hh, ll); h[j] = (short)hh; l[j] = (short)ll; }
    *(short8*)(dh + (size_t)row * 2048 + c) = h;
    *(short8*)(dl + (size_t)row * 2048 + c) = l;
}

// Wcat2 (4096 x 3072): [Wih2 | Whh2]   (384 threads)
__global__ __launch_bounds__(384) void k_build_wcat2(const float* __restrict__ Wih2, const float* __restrict__ Whh2,
                                                     u16* __restrict__ dh, u16* __restrict__ dl) {
    int row = blockIdx.x;
    int c = threadIdx.x * 8;
    const float* src = (c < 2048) ? (Wih2 + (size_t)row * 2048 + c) : (Whh2 + (size_t)row * 1024 + (c - 2048));
    short8 h, l;
#pragma unroll
    for (int j = 0; j < 8; ++j) { u16 hh, ll; split2(src[j], hh, ll); h[j] = (short)hh; l[j] = (short)ll; }
    *(short8*)(dh + (size_t)row * 3072 + c) = h;
    *(short8*)(dl + (size_t)row * 3072 + c) = l;
}

// Wx1 (4096 x 2048) = Wih1[:, 1024:3072]
__global__ __launch_bounds__(256) void k_build_wx1(const float* __restrict__ Wih1, u16* __restrict__ dh,
                                                   u16* __restrict__ dl) {
    int row = blockIdx.x;
    int c = threadIdx.x * 8;
    const float* src = Wih1 + (size_t)row * 3072 + 1024 + c;
    short8 h, l;
#pragma unroll
    for (int j = 0; j < 8; ++j) { u16 hh, ll; split2(src[j], hh, ll); h[j] = (short)hh; l[j] = (short)ll; }
    *(short8*)(dh + (size_t)row * 2048 + c) = h;
    *(short8*)(dl + (size_t)row * 2048 + c) = l;
}

// Xaug (1344 x 2048): [gv | x_t] hi/lo
__global__ __launch_bounds__(256) void k_build_xaug(const float* __restrict__ enc, const int* __restrict__ obj,
                                                    const float* __restrict__ bos_w, u16* __restrict__ dh,
                                                    u16* __restrict__ dl) {
    int b = blockIdx.x, t = blockIdx.y, tid = threadIdx.x;
    const float* gv = enc + (size_t)b * 129 * 1024;
    const float* xr;
    if (t == 0) xr = bos_w;
    else {
        int idx = obj[b * 20 + (t - 1)];
        idx = min(max(idx, 0), 127);
        xr = enc + ((size_t)b * 129 + 1 + idx) * 1024;
    }
    size_t rowoff = ((size_t)b * 21 + t) * 2048;
    float4 v0 = *(const float4*)(gv + tid * 4);
    float4 v1 = *(const float4*)(xr + tid * 4);
    ushort4 h0, l0, h1, l1;
    split2(v0.x, h0.x, l0.x); split2(v0.y, h0.y, l0.y); split2(v0.z, h0.z, l0.z); split2(v0.w, h0.w, l0.w);
    split2(v1.x, h1.x, l1.x); split2(v1.y, h1.y, l1.y); split2(v1.z, h1.z, l1.z); split2(v1.w, h1.w, l1.w);
    *(ushort4*)(dh + rowoff + tid * 4) = h0;
    *(ushort4*)(dl + rowoff + tid * 4) = l0;
    *(ushort4*)(dh + rowoff + 1024 + tid * 4) = h1;
    *(ushort4*)(dl + rowoff + 1024 + tid * 4) = l1;
}

// ---------------- MFMA GEMM: C = A @ W^T + b1 + b2, split-precision passes ----------------
template <int APASS, int BPASS, int AREMAP, bool BF16OUT>
__global__ __launch_bounds__(256)
void k_gemm3(const u16* __restrict__ Ah, const u16* __restrict__ Al, int lda,
             const u16* __restrict__ Wh, const u16* __restrict__ Wl, int ldw,
             const float* __restrict__ b1, const float* __restrict__ b2,
             void* __restrict__ Cout, int ldc, int Mrows, int K) {
    constexpr int NP = APASS + BPASS;
    __shared__ char lds[2][NP][8192];
    const int tid = threadIdx.x;
    const int lane = tid & 63;
    const int lr = lane & 15, lk = lane >> 4;
    const int m0 = blockIdx.y * 128, n0 = blockIdx.x * 128;
    const int wid = tid >> 6;
    const int wr = wid >> 1, wc = wid & 1;
    const int wbyte = (tid & 192) * 16;

    floatx4 acc[4][4] = {};
    const int nt = K >> 5;

    auto stage = [&](int bb, int kt) {
        int k0 = kt * 32;
#pragma unroll
        for (int i = 0; i < 2; ++i) {
            int p = i * 256 + tid;
            int s = p ^ ((p >> 2) & 3);
            int row = s >> 2, kc = s & 3;
            size_t aoff;
            int gm = m0 + row;
            if (AREMAP == 1) aoff = (((size_t)(gm >> 7)) * 129 + 1 + (gm & 127)) * 1024 + k0 + kc * 8;
            else {
                int cm = gm < Mrows ? gm : Mrows - 1;
                aoff = (size_t)cm * lda + k0 + kc * 8;
            }
            gload16(Ah + aoff, &lds[bb][0][i * 4096 + wbyte]);
            if constexpr (APASS == 2) gload16(Al + aoff, &lds[bb][1][i * 4096 + wbyte]);
            size_t woff = (size_t)(n0 + row) * ldw + k0 + kc * 8;
            gload16(Wh + woff, &lds[bb][APASS][i * 4096 + wbyte]);
            if constexpr (BPASS == 2) gload16(Wl + woff, &lds[bb][APASS + 1][i * 4096 + wbyte]);
        }
    };

    stage(0, 0);
    __syncthreads();
    for (int t = 0; t < nt; ++t) {
        int bb = t & 1;
        if (t + 1 < nt) stage(bb ^ 1, t + 1);
        short8 ah_[4], al_[4], bh_[4], bl_[4];
#pragma unroll
        for (int mi = 0; mi < 4; ++mi) {
            int row = wr * 64 + mi * 16 + lr;
            int slot = (row * 4 + (lk ^ (row & 3))) * 16;
            ah_[mi] = *(const short8*)&lds[bb][0][slot];
            if constexpr (APASS == 2) al_[mi] = *(const short8*)&lds[bb][1][slot];
        }
#pragma unroll
        for (int ni = 0; ni < 4; ++ni) {
            int row = wc * 64 + ni * 16 + lr;
            int slot = (row * 4 + (lk ^ (row & 3))) * 16;
            bh_[ni] = *(const short8*)&lds[bb][APASS][slot];
            if constexpr (BPASS == 2) bl_[ni] = *(const short8*)&lds[bb][APASS + 1][slot];
        }
#pragma unroll
        for (int mi = 0; mi < 4; ++mi)
#pragma unroll
            for (int ni = 0; ni < 4; ++ni) {
                acc[mi][ni] = __builtin_amdgcn_mfma_f32_16x16x32_bf16(ah_[mi], bh_[ni], acc[mi][ni], 0, 0, 0);
                if constexpr (BPASS == 2)
                    acc[mi][ni] = __builtin_amdgcn_mfma_f32_16x16x32_bf16(ah_[mi], bl_[ni], acc[mi][ni], 0, 0, 0);
                if constexpr (APASS == 2)
                    acc[mi][ni] = __builtin_amdgcn_mfma_f32_16x16x32_bf16(al_[mi], bh_[ni], acc[mi][ni], 0, 0, 0);
            }
        __syncthreads();
    }
#pragma unroll
    for (int mi = 0; mi < 4; ++mi) {
#pragma unroll
        for (int r = 0; r < 4; ++r) {
            int gm = m0 + wr * 64 + mi * 16 + lk * 4 + r;
            if (AREMAP == 0 && gm >= Mrows) continue;
#pragma unroll
            for (int ni = 0; ni < 4; ++ni) {
                int gn = n0 + wc * 64 + ni * 16 + lr;
                float v = acc[mi][ni][r];
                if (b1) v += b1[gn];
                if (b2) v += b2[gn];
                if (BF16OUT) ((u16*)Cout)[(size_t)gm * ldc + gn] = f2bf(v);
                else ((float*)Cout)[(size_t)gm * ldc + gn] = v;
            }
        }
    }
}

// ---------------- skinny 2-pass GEMM, N-tile 32: P[kp] = X(64 x Klen) @ (Wh+Wl)^T(32 rows) ----------------
__global__ __launch_bounds__(256)
void k_gp2(const u16* __restrict__ Xh, int ldx,
           const u16* __restrict__ Wh, const u16* __restrict__ Wl, int ldw,
           int Klen, float* __restrict__ P, int Ntot) {
    __shared__ char lds[2][8192];  // [Xh 4096 | Wh 2048 | Wl 2048]
    const int tid = threadIdx.x, wid = tid >> 6, lane = tid & 63;
    const int lr = lane & 15, lk = lane >> 4;
    const int n0 = blockIdx.x * 32;
    const int koff = blockIdx.y * Klen;
    floatx4 acc[2] = {};
    const int nt = Klen >> 5;

    const int sX = tid ^ ((tid >> 2) & 3);
    const size_t xoff = (size_t)(sX >> 2) * ldx + (sX & 3) * 8 + koff;
    const int xdst = (tid & 192) * 16;
    const int pw = tid & 127;
    const int sW = pw ^ ((pw >> 2) & 3);
    const size_t woff = (size_t)(n0 + (sW >> 2)) * ldw + (sW & 3) * 8 + koff;
    const u16* Wsrc = (tid < 128) ? Wh : Wl;
    const int wdst = 4096 + (wid >> 1) * 2048 + (wid & 1) * 1024;

    auto stage = [&](int bb, int kt) {
        int k0 = kt * 32;
        gload16(Xh + xoff + k0, &lds[bb][xdst]);
        gload16(Wsrc + woff + k0, &lds[bb][wdst]);
    };

    stage(0, 0);
    __syncthreads();
    for (int t = 0; t < nt; ++t) {
        int bb = t & 1;
        if (t + 1 < nt) stage(bb ^ 1, t + 1);
        int arow = wid * 16 + lr;
        short8 xh = *(const short8*)&lds[bb][(arow * 4 + (lk ^ (arow & 3))) * 16];
#pragma unroll
        for (int ni = 0; ni < 2; ++ni) {
            int r = ni * 16 + lr;
            int slot = (r * 4 + (lk ^ (r & 3))) * 16;
            short8 wh = *(const short8*)&lds[bb][4096 + slot];
            short8 wl = *(const short8*)&lds[bb][6144 + slot];
            acc[ni] = __builtin_amdgcn_mfma_f32_16x16x32_bf16(xh, wh, acc[ni], 0, 0, 0);
            acc[ni] = __builtin_amdgcn_mfma_f32_16x16x32_bf16(xh, wl, acc[ni], 0, 0, 0);
        }
        __syncthreads();
    }
    float* Pb = P + (size_t)blockIdx.y * 64 * Ntot;
#pragma unroll
    for (int ni = 0; ni < 2; ++ni)
#pragma unroll
        for (int r = 0; r < 4; ++r) {
            int b = wid * 16 + lk * 4 + r;
            Pb[(size_t)b * Ntot + n0 + ni * 16 + lr] = acc[ni][r];
        }
}

// ---------------- reduce nP partials + LSTM cell (single-bf16 state outputs) ----------------
__global__ __launch_bounds__(256)
void k_finish(const float* __restrict__ P, int Ntot, int nP, const float* __restrict__ xcf,
              const float* __restrict__ b1, const float* __restrict__ b2,
              float* __restrict__ cst,
              u16* __restrict__ w1, int w1s, u16* __restrict__ w2, int w2s,
              float* __restrict__ outf, u16* __restrict__ oh) {
    int idx = blockIdx.x * 256 + threadIdx.x;  // b*1024 + d
    int b = idx >> 10, d = idx & 1023;
    float g[4];
#pragma unroll
    for (int q = 0; q < 4; ++q) {
        int n = q * 1024 + d;
        float s = 0.f;
        for (int p = 0; p < nP; ++p) s += P[((size_t)p * 64 + b) * Ntot + n];
        if (xcf) s += xcf[(size_t)b * 21 * 4096 + n];
        if (b1) s += b1[n];
        if (b2) s += b2[n];
        g[q] = s;
    }
    float cp = cst[idx];
    float cn = sigm(g[1]) * cp + sigm(g[0]) * ftanh(g[2]);
    float hn = sigm(g[3]) * ftanh(cn);
    cst[idx] = cn;
    u16 hh = f2bf(hn);
    w1[b * w1s + d] = hh;
    w2[b * w2s + d] = hh;
    if (outf) outf[(size_t)b * 21 * 1024 + d] = hn;
    if (oh) oh[(size_t)b * 21 * 1024 + d] = hh;
}

// ---------------- score: wa . tanh(p_att + ah) + ba, mask (bf16 p_att; ah from 4 partials) ----------------
__global__ __launch_bounds__(256)
void k_score(const float* __restrict__ PAH, const float* __restrict__ bah,
             const float* __restrict__ wa, const float* __restrict__ ba,
             const u16* __restrict__ Patt, const int* __restrict__ amask, float* __restrict__ SC) {
    int mc = blockIdx.x, b = blockIdx.y, tid = threadIdx.x;
    __shared__ float sah[1024], swa[1024];
    {
        int d = tid * 4;
        *(float4*)&swa[d] = *(const float4*)(wa + d);
        float4 s;
        float* sp = &s.x;
#pragma unroll
        for (int j = 0; j < 4; ++j) {
            float acc = bah[d + j];
#pragma unroll
            for (int p = 0; p < 4; ++p) acc += PAH[((size_t)p * 64 + b) * 1024 + d + j];
            sp[j] = acc;
        }
        *(float4*)&sah[d] = s;
    }
    __syncthreads();
    int wv = tid >> 6, lane = tid & 63;
    float bav = ba[0];
    for (int j = 0; j < 4; ++j) {
        int m = mc * 16 + wv * 4 + j;
        const u16* pr = Patt + ((size_t)(b * 128 + m)) * 1024;
        float part = 0.f;
#pragma unroll
        for (int c = 0; c < 4; ++c) {
            int d = c * 256 + lane * 4;
            ushort4 p4 = *(const ushort4*)(pr + d);
            float4 a4 = *(const float4*)&sah[d];
            float4 w4 = *(const float4*)&swa[d];
            part += ftanh(bf2f(p4.x) + a4.x) * w4.x + ftanh(bf2f(p4.y) + a4.y) * w4.y +
                    ftanh(bf2f(p4.z) + a4.z) * w4.z + ftanh(bf2f(p4.w) + a4.w) * w4.w;
        }
#pragma unroll
        for (int off = 32; off; off >>= 1) part += __shfl_down(part, off, 64);
        if (lane == 0) {
            float sc = part + bav;
            if (amask[b * 129 + 1 + m] == 0) sc = -1e9f;
            SC[b * 128 + m] = sc;
        }
    }
}

// ---------------- softmax + weighted feature sum (bf16 att_feats) -> X2 att slot ----------------
__global__ __launch_bounds__(256)
void k_attsum(const float* __restrict__ SC, const u16* __restrict__ attf,
              u16* __restrict__ X2h) {
    int dc = blockIdx.x, b = blockIdx.y, tid = threadIdx.x;
    __shared__ float salpha[128];
    __shared__ float sred[8];
    float sv = (tid < 128) ? SC[b * 128 + tid] : -1e30f;
    float mx = sv;
#pragma unroll
    for (int off = 32; off; off >>= 1) mx = fmaxf(mx, __shfl_down(mx, off, 64));
    if ((tid & 63) == 0) sred[tid >> 6] = mx;
    __syncthreads();
    float gmx = fmaxf(fmaxf(sred[0], sred[1]), fmaxf(sred[2], sred[3]));
    float ev = (tid < 128) ? __expf(sv - gmx) : 0.f;
    float s = ev;
#pragma unroll
    for (int off = 32; off; off >>= 1) s += __shfl_down(s, off, 64);
    if ((tid & 63) == 0) sred[4 + (tid >> 6)] = s;
    __syncthreads();
    float gsum = sred[4] + sred[5] + sred[6] + sred[7];
    if (tid < 128) salpha[tid] = ev / gsum;
    __syncthreads();
    int d = dc * 256 + tid;
    const u16* base = attf + (size_t)b * 128 * 1024 + d;
    float acc = 0.f;
#pragma unroll 8
    for (int m = 0; m < 128; ++m) acc += salpha[m] * bf2f(base[(size_t)m * 1024]);
    X2h[b * 3072 + d] = f2bf(acc);
}

// ---------------- nce_logit[b,l,j] = ofe[b,l,:] . afe[b,j,:]  (bf16 OFE/AFE, f32 eos) ----------------
__global__ __launch_bounds__(256)
void k_nce_bf(const u16* __restrict__ OFE, const u16* __restrict__ AFE,
              const float* __restrict__ eos_w, float* __restrict__ nce) {
    int l = blockIdx.x, b = blockIdx.y;
    __shared__ u16 sofe[1024];
    int tid = threadIdx.x;
    *(ushort4*)&sofe[tid * 4] = *(const ushort4*)(OFE + ((size_t)b * 21 + l) * 1024 + tid * 4);
    __syncthreads();
    int w = tid >> 6, lane = tid & 63;
    float* outp = nce + ((size_t)b * 21 + l) * 129;
    for (int j = w; j < 129; j += 4) {
        float part = 0.f;
        if (j == 0) {
#pragma unroll
            for (int c = 0; c < 4; ++c) {
                int d = c * 256 + lane * 4;
                float4 a4 = *(const float4*)(eos_w + d);
                ushort4 o4 = *(const ushort4*)&sofe[d];
                part += a4.x * bf2f(o4.x) + a4.y * bf2f(o4.y) + a4.z * bf2f(o4.z) + a4.w * bf2f(o4.w);
            }
        } else {
            const u16* ar = AFE + ((size_t)b * 128 + (j - 1)) * 1024;
#pragma unroll
            for (int c = 0; c < 4; ++c) {
                int d = c * 256 + lane * 4;
                ushort4 a4 = *(const ushort4*)(ar + d);
                ushort4 o4 = *(const ushort4*)&sofe[d];
                part += bf2f(a4.x) * bf2f(o4.x) + bf2f(a4.y) * bf2f(o4.y) +
                        bf2f(a4.z) * bf2f(o4.z) + bf2f(a4.w) * bf2f(o4.w);
            }
        }
#pragma unroll
        for (int off = 32; off; off >>= 1) part += __shfl_down(part, off, 64);
        if (lane == 0) outp[j] = part;
    }
}

extern "C" void kernel_launch(void* const* d_in, const int* in_sizes, int n_in,
                              void* d_out, int out_size, void* d_ws, size_t ws_size,
                              hipStream_t stream) {
    const float* enc  = (const float*)d_in[0];
    const int*   obj  = (const int*)d_in[1];
    const int*   amask= (const int*)d_in[2];
    const float* bosw = (const float*)d_in[3];
    const float* eosw = (const float*)d_in[4];
    const float* Wp   = (const float*)d_in[5];
    const float* bp   = (const float*)d_in[6];
    const float* Wih1 = (const float*)d_in[7];
    const float* Whh1 = (const float*)d_in[8];
    const float* bih1 = (const float*)d_in[9];
    const float* bhh1 = (const float*)d_in[10];
    const float* Wih2 = (const float*)d_in[11];
    const float* Whh2 = (const float*)d_in[12];
    const float* bih2 = (const float*)d_in[13];
    const float* bhh2 = (const float*)d_in[14];
    const float* Wah  = (const float*)d_in[15];
    const float* bah  = (const float*)d_in[16];
    const float* wa   = (const float*)d_in[17];
    const float* ba   = (const float*)d_in[18];
    const float* Wae  = (const float*)d_in[19];
    const float* bae  = (const float*)d_in[20];
    const float* Woe  = (const float*)d_in[21];
    const float* boe  = (const float*)d_in[22];

    float* outputs = (float*)d_out;                    // (64,21,1024)
    float* nce     = outputs + (size_t)64 * 21 * 1024; // (64,21,129)

    char* wp = (char*)d_ws;
    auto alloc = [&](size_t bytes) -> char* { char* p = wp; wp += (bytes + 255) & ~(size_t)255; return p; };
    u16* encbf  = (u16*)alloc((size_t)64 * 129 * 1024 * 2);   // pre-scan only -> scan-state overlay
    u16* Wpbf   = (u16*)alloc((size_t)1024 * 1024 * 2);
    u16* Xaugh  = (u16*)alloc((size_t)1344 * 2048 * 2);       // pre-scan only -> OFEbf overlay
    u16* Xaugl  = (u16*)alloc((size_t)1344 * 2048 * 2);
    u16* W1h    = (u16*)alloc((size_t)4096 * 2048 * 2);
    u16* W1l    = (u16*)alloc((size_t)4096 * 2048 * 2);
    u16* W2h    = (u16*)alloc((size_t)4096 * 3072 * 2);
    u16* W2l    = (u16*)alloc((size_t)4096 * 3072 * 2);
    u16* Wahh   = (u16*)alloc((size_t)1024 * 1024 * 2);
    u16* Wahl   = (u16*)alloc((size_t)1024 * 1024 * 2);
    u16* Waeh   = (u16*)alloc((size_t)1024 * 1024 * 2);
    u16* Wael   = (u16*)alloc((size_t)1024 * 1024 * 2);
    u16* Woeh   = (u16*)alloc((size_t)1024 * 1024 * 2);
    u16* Woel   = (u16*)alloc((size_t)1024 * 1024 * 2);
    // region1: Wx1 hi/lo (33.5MB); after Xc GEMM reused for AFEbf (16.8MB)
    char* region1 = alloc((size_t)2 * 4096 * 2048 * 2);
    u16* Wx1h = (u16*)region1;
    u16* Wx1l = (u16*)region1 + (size_t)4096 * 2048;
    u16* AFEbf = (u16*)region1;
    u16* PattBf  = (u16*)alloc((size_t)8192 * 1024 * 2);
    u16* attfbf  = (u16*)alloc((size_t)64 * 128 * 1024 * 2);
    float* Xcf   = (float*)alloc((size_t)1344 * 4096 * 4);
    u16* Xouth   = (u16*)alloc((size_t)1344 * 1024 * 2);
    float* P2    = (float*)alloc((size_t)4 * 64 * 4096 * 4);
    // OFEbf overlays Xaugh (Xaug dead after Xc GEMM)
    u16* OFEbf = Xaugh;
    // scan-state overlays encbf (encbf dead after pre-scan GEMMs)
    char* sp2 = (char*)encbf;
    auto alloc2 = [&](size_t bytes) -> char* { char* p = sp2; sp2 += (bytes + 255) & ~(size_t)255; return p; };
    float* P1  = (float*)alloc2((size_t)4 * 64 * 4096 * 4);
    float* PAH = (float*)alloc2((size_t)4 * 64 * 1024 * 4);
    u16* XHh   = (u16*)alloc2((size_t)64 * 2048 * 2);   // [h2 | h1]
    u16* X2h   = (u16*)alloc2((size_t)64 * 3072 * 2);   // [att | h1 | h2]
    float* c1  = (float*)alloc2((size_t)64 * 1024 * 4);
    float* c2  = (float*)alloc2((size_t)64 * 1024 * 4);
    float* SC  = (float*)alloc2((size_t)64 * 128 * 4);

    dim3 blk(256);
    // prep (encbf region live here; scan-state memsets deferred until after pre-scan GEMMs)
    k_cvt<<<2048, blk, 0, stream>>>(enc, encbf, 64 * 129 * 1024 / 4);
    k_cvt_att<<<dim3(128, 64), blk, 0, stream>>>(enc, attfbf);
    k_cvt<<<1024, blk, 0, stream>>>(Wp, Wpbf, 1024 * 1024 / 4);
    k_splitp<<<1024, blk, 0, stream>>>(Wah, Wahh, Wahl, 1024 * 1024 / 4);
    k_splitp<<<1024, blk, 0, stream>>>(Wae, Waeh, Wael, 1024 * 1024 / 4);
    k_splitp<<<1024, blk, 0, stream>>>(Woe, Woeh, Woel, 1024 * 1024 / 4);
    k_build_wx1<<<4096, blk, 0, stream>>>(Wih1, Wx1h, Wx1l);
    k_build_w1cat<<<4096, blk, 0, stream>>>(Wih1, Whh1, W1h, W1l);
    k_build_wcat2<<<4096, dim3(384), 0, stream>>>(Wih2, Whh2, W2h, W2l);
    k_build_xaug<<<dim3(64, 21), blk, 0, stream>>>(enc, obj, bosw, Xaugh, Xaugl);

    // p_att (bf16 out, single-pass Wp): att_feats @ Wp^T + bp
    k_gemm3<1, 1, 1, true><<<dim3(8, 64), blk, 0, stream>>>(
        encbf, nullptr, 0, Wpbf, nullptr, 1024, bp, nullptr, PattBf, 1024, 8192, 1024);
    // Xc (A+W split, f32 out): Xaug @ Wx1^T + bih1 + bhh1   (reads region1 as Wx1)
    k_gemm3<2, 2, 0, false><<<dim3(32, 11), blk, 0, stream>>>(
        Xaugh, Xaugl, 2048, Wx1h, Wx1l, 2048, bih1, bhh1, Xcf, 4096, 1344, 2048);
    // afe (bf16 out, Wae split): att_feats @ Wae^T + bae   (writes region1 as AFEbf)
    k_gemm3<1, 2, 1, true><<<dim3(8, 64), blk, 0, stream>>>(
        encbf, nullptr, 0, Waeh, Wael, 1024, bae, nullptr, AFEbf, 1024, 8192, 1024);

    // scan-state init (encbf now dead)
    hipMemsetAsync(XHh, 0, (size_t)64 * 2048 * 2, stream);
    hipMemsetAsync(X2h, 0, (size_t)64 * 3072 * 2, stream);
    hipMemsetAsync(c1, 0, (size_t)64 * 1024 * 4, stream);
    hipMemsetAsync(c2, 0, (size_t)64 * 1024 * 4, stream);

    for (int t = 0; t < 21; ++t) {
        // cell1 gates: [h2|h1] @ (W1h+W1l)^T (4096x2048), N-tile 32, K-split 4, 2-pass
        k_gp2<<<dim3(128, 4), blk, 0, stream>>>(XHh, 2048, W1h, W1l, 2048, 512, P1, 4096);
        // LSTM1 finish: + Xc addend (carries biases); h1 -> XH[:,1024:], X2[:,1024:2048]
        k_finish<<<256, blk, 0, stream>>>(P1, 4096, 4, Xcf + (size_t)t * 4096, nullptr, nullptr,
                                          c1, XHh + 1024, 2048, X2h + 1024, 3072, nullptr, nullptr);
        // ah = h1_new @ (Wahh+Wahl)^T, N-tile 32, K-split 4
        k_gp2<<<dim3(32, 4), blk, 0, stream>>>(XHh + 1024, 2048, Wahh, Wahl, 1024, 256, PAH, 1024);
        k_score<<<dim3(8, 64), blk, 0, stream>>>(PAH, bah, wa, ba, PattBf, amask, SC);
        k_attsum<<<dim3(4, 64), blk, 0, stream>>>(SC, attfbf, X2h);
        // cell2 gates: [att|h1|h2] @ (W2h+W2l)^T (4096x3072), N-tile 32, K-split 4, 2-pass
        k_gp2<<<dim3(128, 4), blk, 0, stream>>>(X2h, 3072, W2h, W2l, 3072, 768, P2, 4096);
        // LSTM2 finish: h2 -> XH[:,0:], X2[:,2048:], outputs, Xout
        k_finish<<<256, blk, 0, stream>>>(P2, 4096, 4, nullptr, bih2, bhh2,
                                          c2, XHh, 2048, X2h + 2048, 3072,
                                          outputs + (size_t)t * 1024, Xouth + (size_t)t * 1024);
    }

    // ofe = outputs @ Woe^T + boe (bf16 out; overlays dead Xaug region)
    k_gemm3<1, 2, 0, true><<<dim3(8, 11), blk, 0, stream>>>(
        Xouth, nullptr, 1024, Woeh, Woel, 1024, boe, nullptr, OFEbf, 1024, 1344, 1024);
    k_nce_bf<<<dim3(21, 64), blk, 0, stream>>>(OFEbf, AFEbf, eosw, nce);
}

// Round 16
// 1559.357 us; speedup vs baseline: 1.4364x; 1.0209x over previous
//
#include <hip/hip_runtime.h>
#include <cmath>

typedef unsigned short u16;
typedef __attribute__((ext_vector_type(8))) short short8;
typedef __attribute__((ext_vector_type(4))) float floatx4;
typedef __attribute__((address_space(3))) unsigned int lds_u32;
typedef const __attribute__((address_space(1))) unsigned int glob_u32;

__device__ __forceinline__ u16 f2bf(float f) {
    unsigned u = __float_as_uint(f);
    unsigned r = u + 0x7fffu + ((u >> 16) & 1u);
    return (u16)(r >> 16);
}
__device__ __forceinline__ float bf2f(u16 h) { return __uint_as_float(((unsigned)h) << 16); }
__device__ __forceinline__ void split2(float x, u16& hi, u16& lo) {
    hi = f2bf(x);
    lo = f2bf(x - bf2f(hi));
}
__device__ __forceinline__ float sigm(float x) {
    x = fminf(fmaxf(x, -30.f), 30.f);
    return 1.0f / (1.0f + __expf(-x));
}
__device__ __forceinline__ float ftanh(float x) {
    x = fminf(fmaxf(x, -15.f), 15.f);
    float e = __expf(2.f * x);
    return (e - 1.f) / (e + 1.f);
}
__device__ __forceinline__ void gload16(const void* g, void* l) {
    __builtin_amdgcn_global_load_lds((glob_u32*)g, (lds_u32*)l, 16, 0, 0);
}

// ---------------- f32 -> bf16 (single) ----------------
__global__ __launch_bounds__(256) void k_cvt(const float* __restrict__ s, u16* __restrict__ d, int n4) {
    int i = blockIdx.x * 256 + threadIdx.x;
    int stride = gridDim.x * 256;
    for (; i < n4; i += stride) {
        float4 v = ((const float4*)s)[i];
        ushort4 o;
        o.x = f2bf(v.x); o.y = f2bf(v.y); o.z = f2bf(v.z); o.w = f2bf(v.w);
        ((ushort4*)d)[i] = o;
    }
}

// ---------------- f32 -> (hi, lo) bf16 planes ----------------
__global__ __launch_bounds__(256) void k_splitp(const float* __restrict__ s, u16* __restrict__ hi,
                                                u16* __restrict__ lo, int n4) {
    int i = blockIdx.x * 256 + threadIdx.x;
    int stride = gridDim.x * 256;
    for (; i < n4; i += stride) {
        float4 v = ((const float4*)s)[i];
        ushort4 h, l;
        split2(v.x, h.x, l.x); split2(v.y, h.y, l.y);
        split2(v.z, h.z, l.z); split2(v.w, h.w, l.w);
        ((ushort4*)hi)[i] = h;
        ((ushort4*)lo)[i] = l;
    }
}

// ---------------- weight concat builders (hi/lo planes) ----------------
// W1cat (4096 x 2048): [Wih1[:, :1024] | Whh1]
__global__ __launch_bounds__(256) void k_build_w1cat(const float* __restrict__ Wih1, const float* __restrict__ Whh1,
                                                     u16* __restrict__ dh, u16* __restrict__ dl) {
    int row = blockIdx.x;
    int c = threadIdx.x * 8;
    const float* src = (c < 1024) ? (Wih1 + (size_t)row * 3072 + c) : (Whh1 + (size_t)row * 1024 + (c - 1024));
    short8 h, l;
#pragma unroll
    for (int j = 0; j < 8; ++j) { u16 hh, ll; split2(src[j], hh, ll); h[j] = (short)hh; l[j] = (short)ll; }
    *(short8*)(dh + (size_t)row * 2048 + c) = h;
    *(short8*)(dl + (size_t)row * 2048 + c) = l;
}

// Wcat2 (4096 x 3072): [Wih2 | Whh2]   (384 threads)
__global__ __launch_bounds__(384) void k_build_wcat2(const float* __restrict__ Wih2, const float* __restrict__ Whh2,
                                                     u16* __restrict__ dh, u16* __restrict__ dl) {
    int row = blockIdx.x;
    int c = threadIdx.x * 8;
    const float* src = (c < 2048) ? (Wih2 + (size_t)row * 2048 + c) : (Whh2 + (size_t)row * 1024 + (c - 2048));
    short8 h, l;
#pragma unroll
    for (int j = 0; j < 8; ++j) { u16 hh, ll; split2(src[j], hh, ll); h[j] = (short)hh; l[j] = (short)ll; }
    *(short8*)(dh + (size_t)row * 3072 + c) = h;
    *(short8*)(dl + (size_t)row * 3072 + c) = l;
}

// Wx1 (4096 x 2048) = Wih1[:, 1024:3072]
__global__ __launch_bounds__(256) void k_build_wx1(const float* __restrict__ Wih1, u16* __restrict__ dh,
                                                   u16* __restrict__ dl) {
    int row = blockIdx.x;
    int c = threadIdx.x * 8;
    const float* src = Wih1 + (size_t)row * 3072 + 1024 + c;
    short8 h, l;
#pragma unroll
    for (int j = 0; j < 8; ++j) { u16 hh, ll; split2(src[j], hh, ll); h[j] = (short)hh; l[j] = (short)ll; }
    *(short8*)(dh + (size_t)row * 2048 + c) = h;
    *(short8*)(dl + (size_t)row * 2048 + c) = l;
}

// Xaug (1344 x 2048): [gv | x_t] hi/lo
__global__ __launch_bounds__(256) void k_build_xaug(const float* __restrict__ enc, const int* __restrict__ obj,
                                                    const float* __restrict__ bos_w, u16* __restrict__ dh,
                                                    u16* __restrict__ dl) {
    int b = blockIdx.x, t = blockIdx.y, tid = threadIdx.x;
    const float* gv = enc + (size_t)b * 129 * 1024;
    const float* xr;
    if (t == 0) xr = bos_w;
    else {
        int idx = obj[b * 20 + (t - 1)];
        idx = min(max(idx, 0), 127);
        xr = enc + ((size_t)b * 129 + 1 + idx) * 1024;
    }
    size_t rowoff = ((size_t)b * 21 + t) * 2048;
    float4 v0 = *(const float4*)(gv + tid * 4);
    float4 v1 = *(const float4*)(xr + tid * 4);
    ushort4 h0, l0, h1, l1;
    split2(v0.x, h0.x, l0.x); split2(v0.y, h0.y, l0.y); split2(v0.z, h0.z, l0.z); split2(v0.w, h0.w, l0.w);
    split2(v1.x, h1.x, l1.x); split2(v1.y, h1.y, l1.y); split2(v1.z, h1.z, l1.z); split2(v1.w, h1.w, l1.w);
    *(ushort4*)(dh + rowoff + tid * 4) = h0;
    *(ushort4*)(dl + rowoff + tid * 4) = l0;
    *(ushort4*)(dh + rowoff + 1024 + tid * 4) = h1;
    *(ushort4*)(dl + rowoff + 1024 + tid * 4) = l1;
}

// ---------------- MFMA GEMM: C = A @ W^T + b1 + b2, split-precision passes ----------------
template <int APASS, int BPASS, int AREMAP, bool BF16OUT>
__global__ __launch_bounds__(256)
void k_gemm3(const u16* __restrict__ Ah, const u16* __restrict__ Al, int lda,
             const u16* __restrict__ Wh, const u16* __restrict__ Wl, int ldw,
             const float* __restrict__ b1, const float* __restrict__ b2,
             void* __restrict__ Cout, int ldc, int Mrows, int K) {
    constexpr int NP = APASS + BPASS;
    __shared__ char lds[2][NP][8192];
    const int tid = threadIdx.x;
    const int lane = tid & 63;
    const int lr = lane & 15, lk = lane >> 4;
    const int m0 = blockIdx.y * 128, n0 = blockIdx.x * 128;
    const int wid = tid >> 6;
    const int wr = wid >> 1, wc = wid & 1;
    const int wbyte = (tid & 192) * 16;

    floatx4 acc[4][4] = {};
    const int nt = K >> 5;

    auto stage = [&](int bb, int kt) {
        int k0 = kt * 32;
#pragma unroll
        for (int i = 0; i < 2; ++i) {
            int p = i * 256 + tid;
            int s = p ^ ((p >> 2) & 3);
            int row = s >> 2, kc = s & 3;
            size_t aoff;
            int gm = m0 + row;
            if (AREMAP == 1) aoff = (((size_t)(gm >> 7)) * 129 + 1 + (gm & 127)) * 1024 + k0 + kc * 8;
            else {
                int cm = gm < Mrows ? gm : Mrows - 1;
                aoff = (size_t)cm * lda + k0 + kc * 8;
            }
            gload16(Ah + aoff, &lds[bb][0][i * 4096 + wbyte]);
            if constexpr (APASS == 2) gload16(Al + aoff, &lds[bb][1][i * 4096 + wbyte]);
            size_t woff = (size_t)(n0 + row) * ldw + k0 + kc * 8;
            gload16(Wh + woff, &lds[bb][APASS][i * 4096 + wbyte]);
            if constexpr (BPASS == 2) gload16(Wl + woff, &lds[bb][APASS + 1][i * 4096 + wbyte]);
        }
    };

    stage(0, 0);
    __syncthreads();
    for (int t = 0; t < nt; ++t) {
        int bb = t & 1;
        if (t + 1 < nt) stage(bb ^ 1, t + 1);
        short8 ah_[4], al_[4], bh_[4], bl_[4];
#pragma unroll
        for (int mi = 0; mi < 4; ++mi) {
            int row = wr * 64 + mi * 16 + lr;
            int slot = (row * 4 + (lk ^ (row & 3))) * 16;
            ah_[mi] = *(const short8*)&lds[bb][0][slot];
            if constexpr (APASS == 2) al_[mi] = *(const short8*)&lds[bb][1][slot];
        }
#pragma unroll
        for (int ni = 0; ni < 4; ++ni) {
            int row = wc * 64 + ni * 16 + lr;
            int slot = (row * 4 + (lk ^ (row & 3))) * 16;
            bh_[ni] = *(const short8*)&lds[bb][APASS][slot];
            if constexpr (BPASS == 2) bl_[ni] = *(const short8*)&lds[bb][APASS + 1][slot];
        }
#pragma unroll
        for (int mi = 0; mi < 4; ++mi)
#pragma unroll
            for (int ni = 0; ni < 4; ++ni) {
                acc[mi][ni] = __builtin_amdgcn_mfma_f32_16x16x32_bf16(ah_[mi], bh_[ni], acc[mi][ni], 0, 0, 0);
                if constexpr (BPASS == 2)
                    acc[mi][ni] = __builtin_amdgcn_mfma_f32_16x16x32_bf16(ah_[mi], bl_[ni], acc[mi][ni], 0, 0, 0);
                if constexpr (APASS == 2)
                    acc[mi][ni] = __builtin_amdgcn_mfma_f32_16x16x32_bf16(al_[mi], bh_[ni], acc[mi][ni], 0, 0, 0);
            }
        __syncthreads();
    }
#pragma unroll
    for (int mi = 0; mi < 4; ++mi) {
#pragma unroll
        for (int r = 0; r < 4; ++r) {
            int gm = m0 + wr * 64 + mi * 16 + lk * 4 + r;
            if (AREMAP == 0 && gm >= Mrows) continue;
#pragma unroll
            for (int ni = 0; ni < 4; ++ni) {
                int gn = n0 + wc * 64 + ni * 16 + lr;
                float v = acc[mi][ni][r];
                if (b1) v += b1[gn];
                if (b2) v += b2[gn];
                if (BF16OUT) ((u16*)Cout)[(size_t)gm * ldc + gn] = f2bf(v);
                else ((float*)Cout)[(size_t)gm * ldc + gn] = v;
            }
        }
    }
}

// ---------------- skinny 2-pass GEMM, N-tile 32: P[kp] = X(64 x Klen) @ (Wh+Wl)^T(32 rows) ----------------
__global__ __launch_bounds__(256)
void k_gp2(const u16* __restrict__ Xh, int ldx,
           const u16* __restrict__ Wh, const u16* __restrict__ Wl, int ldw,
           int Klen, float* __restrict__ P, int Ntot) {
    __shared__ char lds[2][8192];  // [Xh 4096 | Wh 2048 | Wl 2048]
    const int tid = threadIdx.x, wid = tid >> 6, lane = tid & 63;
    const int lr = lane & 15, lk = lane >> 4;
    const int n0 = blockIdx.x * 32;
    const int koff = blockIdx.y * Klen;
    floatx4 acc[2] = {};
    const int nt = Klen >> 5;

    const int sX = tid ^ ((tid >> 2) & 3);
    const size_t xoff = (size_t)(sX >> 2) * ldx + (sX & 3) * 8 + koff;
    const int xdst = (tid & 192) * 16;
    const int pw = tid & 127;
    const int sW = pw ^ ((pw >> 2) & 3);
    const size_t woff = (size_t)(n0 + (sW >> 2)) * ldw + (sW & 3) * 8 + koff;
    const u16* Wsrc = (tid < 128) ? Wh : Wl;
    const int wdst = 4096 + (wid >> 1) * 2048 + (wid & 1) * 1024;

    auto stage = [&](int bb, int kt) {
        int k0 = kt * 32;
        gload16(Xh + xoff + k0, &lds[bb][xdst]);
        gload16(Wsrc + woff + k0, &lds[bb][wdst]);
    };

    stage(0, 0);
    __syncthreads();
    for (int t = 0; t < nt; ++t) {
        int bb = t & 1;
        if (t + 1 < nt) stage(bb ^ 1, t + 1);
        int arow = wid * 16 + lr;
        short8 xh = *(const short8*)&lds[bb][(arow * 4 + (lk ^ (arow & 3))) * 16];
#pragma unroll
        for (int ni = 0; ni < 2; ++ni) {
            int r = ni * 16 + lr;
            int slot = (r * 4 + (lk ^ (r & 3))) * 16;
            short8 wh = *(const short8*)&lds[bb][4096 + slot];
            short8 wl = *(const short8*)&lds[bb][6144 + slot];
            acc[ni] = __builtin_amdgcn_mfma_f32_16x16x32_bf16(xh, wh, acc[ni], 0, 0, 0);
            acc[ni] = __builtin_amdgcn_mfma_f32_16x16x32_bf16(xh, wl, acc[ni], 0, 0, 0);
        }
        __syncthreads();
    }
    float* Pb = P + (size_t)blockIdx.y * 64 * Ntot;
#pragma unroll
    for (int ni = 0; ni < 2; ++ni)
#pragma unroll
        for (int r = 0; r < 4; ++r) {
            int b = wid * 16 + lk * 4 + r;
            Pb[(size_t)b * Ntot + n0 + ni * 16 + lr] = acc[ni][r];
        }
}

// ---------------- reduce nP partials + LSTM cell (single-bf16 state outputs) ----------------
__global__ __launch_bounds__(256)
void k_finish(const float* __restrict__ P, int Ntot, int nP, const float* __restrict__ xcf,
              const float* __restrict__ b1, const float* __restrict__ b2,
              float* __restrict__ cst,
              u16* __restrict__ w1, int w1s, u16* __restrict__ w2, int w2s,
              float* __restrict__ outf, u16* __restrict__ oh) {
    int idx = blockIdx.x * 256 + threadIdx.x;  // b*1024 + d
    int b = idx >> 10, d = idx & 1023;
    float g[4];
#pragma unroll
    for (int q = 0; q < 4; ++q) {
        int n = q * 1024 + d;
        float s = 0.f;
        for (int p = 0; p < nP; ++p) s += P[((size_t)p * 64 + b) * Ntot + n];
        if (xcf) s += xcf[(size_t)b * 21 * 4096 + n];
        if (b1) s += b1[n];
        if (b2) s += b2[n];
        g[q] = s;
    }
    float cp = cst[idx];
    float cn = sigm(g[1]) * cp + sigm(g[0]) * ftanh(g[2]);
    float hn = sigm(g[3]) * ftanh(cn);
    cst[idx] = cn;
    u16 hh = f2bf(hn);
    w1[b * w1s + d] = hh;
    w2[b * w2s + d] = hh;
    if (outf) outf[(size_t)b * 21 * 1024 + d] = hn;
    if (oh) oh[(size_t)b * 21 * 1024 + d] = hh;
}

// ---------------- score: wa . tanh(p_att + ah) + ba, mask (bf16 p_att; ah from 4 partials) ----------------
__global__ __launch_bounds__(256)
void k_score(const float* __restrict__ PAH, const float* __restrict__ bah,
             const float* __restrict__ wa, const float* __restrict__ ba,
             const u16* __restrict__ Patt, const int* __restrict__ amask, float* __restrict__ SC) {
    int mc = blockIdx.x, b = blockIdx.y, tid = threadIdx.x;
    __shared__ float sah[1024], swa[1024];
    {
        int d = tid * 4;
        *(float4*)&swa[d] = *(const float4*)(wa + d);
        float4 s;
        float* sp = &s.x;
#pragma unroll
        for (int j = 0; j < 4; ++j) {
            float acc = bah[d + j];
#pragma unroll
            for (int p = 0; p < 4; ++p) acc += PAH[((size_t)p * 64 + b) * 1024 + d + j];
            sp[j] = acc;
        }
        *(float4*)&sah[d] = s;
    }
    __syncthreads();
    int wv = tid >> 6, lane = tid & 63;
    float bav = ba[0];
    for (int j = 0; j < 4; ++j) {
        int m = mc * 16 + wv * 4 + j;
        const u16* pr = Patt + ((size_t)(b * 128 + m)) * 1024;
        float part = 0.f;
#pragma unroll
        for (int c = 0; c < 4; ++c) {
            int d = c * 256 + lane * 4;
            ushort4 p4 = *(const ushort4*)(pr + d);
            float4 a4 = *(const float4*)&sah[d];
            float4 w4 = *(const float4*)&swa[d];
            part += ftanh(bf2f(p4.x) + a4.x) * w4.x + ftanh(bf2f(p4.y) + a4.y) * w4.y +
                    ftanh(bf2f(p4.z) + a4.z) * w4.z + ftanh(bf2f(p4.w) + a4.w) * w4.w;
        }
#pragma unroll
        for (int off = 32; off; off >>= 1) part += __shfl_down(part, off, 64);
        if (lane == 0) {
            float sc = part + bav;
            if (amask[b * 129 + 1 + m] == 0) sc = -1e9f;
            SC[b * 128 + m] = sc;
        }
    }
}

// ---------------- softmax + weighted feature sum (bf16 enc view, 129-row pitch) -> X2 att slot ----------------
__global__ __launch_bounds__(256)
void k_attsum(const float* __restrict__ SC, const u16* __restrict__ encbf,
              u16* __restrict__ X2h) {
    int dc = blockIdx.x, b = blockIdx.y, tid = threadIdx.x;
    __shared__ float salpha[128];
    __shared__ float sred[8];
    float sv = (tid < 128) ? SC[b * 128 + tid] : -1e30f;
    float mx = sv;
#pragma unroll
    for (int off = 32; off; off >>= 1) mx = fmaxf(mx, __shfl_down(mx, off, 64));
    if ((tid & 63) == 0) sred[tid >> 6] = mx;
    __syncthreads();
    float gmx = fmaxf(fmaxf(sred[0], sred[1]), fmaxf(sred[2], sred[3]));
    float ev = (tid < 128) ? __expf(sv - gmx) : 0.f;
    float s = ev;
#pragma unroll
    for (int off = 32; off; off >>= 1) s += __shfl_down(s, off, 64);
    if ((tid & 63) == 0) sred[4 + (tid >> 6)] = s;
    __syncthreads();
    float gsum = sred[4] + sred[5] + sred[6] + sred[7];
    if (tid < 128) salpha[tid] = ev / gsum;
    __syncthreads();
    int d = dc * 256 + tid;
    const u16* base = encbf + ((size_t)b * 129 + 1) * 1024 + d;
    float acc = 0.f;
#pragma unroll 8
    for (int m = 0; m < 128; ++m) acc += salpha[m] * bf2f(base[(size_t)m * 1024]);
    X2h[b * 3072 + d] = f2bf(acc);
}

// ---------------- nce_logit[b,l,j] = ofe[b,l,:] . afe[b,j,:]  (bf16 OFE/AFE, f32 eos) ----------------
__global__ __launch_bounds__(256)
void k_nce_bf(const u16* __restrict__ OFE, const u16* __restrict__ AFE,
              const float* __restrict__ eos_w, float* __restrict__ nce) {
    int l = blockIdx.x, b = blockIdx.y;
    __shared__ u16 sofe[1024];
    int tid = threadIdx.x;
    *(ushort4*)&sofe[tid * 4] = *(const ushort4*)(OFE + ((size_t)b * 21 + l) * 1024 + tid * 4);
    __syncthreads();
    int w = tid >> 6, lane = tid & 63;
    float* outp = nce + ((size_t)b * 21 + l) * 129;
    for (int j = w; j < 129; j += 4) {
        float part = 0.f;
        if (j == 0) {
#pragma unroll
            for (int c = 0; c < 4; ++c) {
                int d = c * 256 + lane * 4;
                float4 a4 = *(const float4*)(eos_w + d);
                ushort4 o4 = *(const ushort4*)&sofe[d];
                part += a4.x * bf2f(o4.x) + a4.y * bf2f(o4.y) + a4.z * bf2f(o4.z) + a4.w * bf2f(o4.w);
            }
        } else {
            const u16* ar = AFE + ((size_t)b * 128 + (j - 1)) * 1024;
#pragma unroll
            for (int c = 0; c < 4; ++c) {
                int d = c * 256 + lane * 4;
                ushort4 a4 = *(const ushort4*)(ar + d);
                ushort4 o4 = *(const ushort4*)&sofe[d];
                part += bf2f(a4.x) * bf2f(o4.x) + bf2f(a4.y) * bf2f(o4.y) +
                        bf2f(a4.z) * bf2f(o4.z) + bf2f(a4.w) * bf2f(o4.w);
            }
        }
#pragma unroll
        for (int off = 32; off; off >>= 1) part += __shfl_down(part, off, 64);
        if (lane == 0) outp[j] = part;
    }
}

extern "C" void kernel_launch(void* const* d_in, const int* in_sizes, int n_in,
                              void* d_out, int out_size, void* d_ws, size_t ws_size,
                              hipStream_t stream) {
    const float* enc  = (const float*)d_in[0];
    const int*   obj  = (const int*)d_in[1];
    const int*   amask= (const int*)d_in[2];
    const float* bosw = (const float*)d_in[3];
    const float* eosw = (const float*)d_in[4];
    const float* Wp   = (const float*)d_in[5];
    const float* bp   = (const float*)d_in[6];
    const float* Wih1 = (const float*)d_in[7];
    const float* Whh1 = (const float*)d_in[8];
    const float* bih1 = (const float*)d_in[9];
    const float* bhh1 = (const float*)d_in[10];
    const float* Wih2 = (const float*)d_in[11];
    const float* Whh2 = (const float*)d_in[12];
    const float* bih2 = (const float*)d_in[13];
    const float* bhh2 = (const float*)d_in[14];
    const float* Wah  = (const float*)d_in[15];
    const float* bah  = (const float*)d_in[16];
    const float* wa   = (const float*)d_in[17];
    const float* ba   = (const float*)d_in[18];
    const float* Wae  = (const float*)d_in[19];
    const float* bae  = (const float*)d_in[20];
    const float* Woe  = (const float*)d_in[21];
    const float* boe  = (const float*)d_in[22];

    float* outputs = (float*)d_out;                    // (64,21,1024)
    float* nce     = outputs + (size_t)64 * 21 * 1024; // (64,21,129)

    char* wp = (char*)d_ws;
    auto alloc = [&](size_t bytes) -> char* { char* p = wp; wp += (bytes + 255) & ~(size_t)255; return p; };
    u16* encbf  = (u16*)alloc((size_t)64 * 129 * 1024 * 2);   // live through whole run (attsum reads it)
    u16* Wpbf   = (u16*)alloc((size_t)1024 * 1024 * 2);
    u16* Xaugh  = (u16*)alloc((size_t)1344 * 2048 * 2);       // pre-scan only -> OFEbf overlay
    u16* Xaugl  = (u16*)alloc((size_t)1344 * 2048 * 2);
    u16* W1h    = (u16*)alloc((size_t)4096 * 2048 * 2);
    u16* W1l    = (u16*)alloc((size_t)4096 * 2048 * 2);
    u16* W2h    = (u16*)alloc((size_t)4096 * 3072 * 2);
    u16* W2l    = (u16*)alloc((size_t)4096 * 3072 * 2);
    u16* Wahh   = (u16*)alloc((size_t)1024 * 1024 * 2);
    u16* Wahl   = (u16*)alloc((size_t)1024 * 1024 * 2);
    u16* Waebf  = (u16*)alloc((size_t)1024 * 1024 * 2);
    u16* Woebf  = (u16*)alloc((size_t)1024 * 1024 * 2);
    // region1: Wx1 hi/lo (33.5MB); after Xc GEMM reused for AFEbf (16.8MB)
    char* region1 = alloc((size_t)2 * 4096 * 2048 * 2);
    u16* Wx1h = (u16*)region1;
    u16* Wx1l = (u16*)region1 + (size_t)4096 * 2048;
    u16* AFEbf = (u16*)region1;
    u16* PattBf  = (u16*)alloc((size_t)8192 * 1024 * 2);
    float* Xcf   = (float*)alloc((size_t)1344 * 4096 * 4);
    u16* Xouth   = (u16*)alloc((size_t)1344 * 1024 * 2);
    float* P2    = (float*)alloc((size_t)4 * 64 * 4096 * 4);
    float* P1    = (float*)alloc((size_t)4 * 64 * 4096 * 4);
    float* PAH   = (float*)alloc((size_t)4 * 64 * 1024 * 4);
    u16* XHh     = (u16*)alloc((size_t)64 * 2048 * 2);   // [h2 | h1]
    u16* X2h     = (u16*)alloc((size_t)64 * 3072 * 2);   // [att | h1 | h2]
    float* c1    = (float*)alloc((size_t)64 * 1024 * 4);
    float* c2    = (float*)alloc((size_t)64 * 1024 * 4);
    float* SC    = (float*)alloc((size_t)64 * 128 * 4);
    // OFEbf overlays Xaugh (Xaug dead after Xc GEMM)
    u16* OFEbf = Xaugh;

    dim3 blk(256);
    // prep
    k_cvt<<<2048, blk, 0, stream>>>(enc, encbf, 64 * 129 * 1024 / 4);
    k_cvt<<<1024, blk, 0, stream>>>(Wp, Wpbf, 1024 * 1024 / 4);
    k_cvt<<<1024, blk, 0, stream>>>(Wae, Waebf, 1024 * 1024 / 4);
    k_cvt<<<1024, blk, 0, stream>>>(Woe, Woebf, 1024 * 1024 / 4);
    k_splitp<<<1024, blk, 0, stream>>>(Wah, Wahh, Wahl, 1024 * 1024 / 4);
    k_build_wx1<<<4096, blk, 0, stream>>>(Wih1, Wx1h, Wx1l);
    k_build_w1cat<<<4096, blk, 0, stream>>>(Wih1, Whh1, W1h, W1l);
    k_build_wcat2<<<4096, dim3(384), 0, stream>>>(Wih2, Whh2, W2h, W2l);
    k_build_xaug<<<dim3(64, 21), blk, 0, stream>>>(enc, obj, bosw, Xaugh, Xaugl);

    // p_att (bf16 out, single-pass Wp): att_feats @ Wp^T + bp
    k_gemm3<1, 1, 1, true><<<dim3(8, 64), blk, 0, stream>>>(
        encbf, nullptr, 0, Wpbf, nullptr, 1024, bp, nullptr, PattBf, 1024, 8192, 1024);
    // Xc (A+W split, f32 out): Xaug @ Wx1^T + bih1 + bhh1   (reads region1 as Wx1)
    k_gemm3<2, 2, 0, false><<<dim3(32, 11), blk, 0, stream>>>(
        Xaugh, Xaugl, 2048, Wx1h, Wx1l, 2048, bih1, bhh1, Xcf, 4096, 1344, 2048);
    // afe (bf16 out, single-pass Wae): att_feats @ Wae^T + bae   (writes region1 as AFEbf)
    k_gemm3<1, 1, 1, true><<<dim3(8, 64), blk, 0, stream>>>(
        encbf, nullptr, 0, Waebf, nullptr, 1024, bae, nullptr, AFEbf, 1024, 8192, 1024);

    // scan-state init
    hipMemsetAsync(XHh, 0, (size_t)64 * 2048 * 2, stream);
    hipMemsetAsync(X2h, 0, (size_t)64 * 3072 * 2, stream);
    hipMemsetAsync(c1, 0, (size_t)64 * 1024 * 4, stream);
    hipMemsetAsync(c2, 0, (size_t)64 * 1024 * 4, stream);

    for (int t = 0; t < 21; ++t) {
        // cell1 gates: [h2|h1] @ (W1h+W1l)^T (4096x2048), N-tile 32, K-split 4, 2-pass
        k_gp2<<<dim3(128, 4), blk, 0, stream>>>(XHh, 2048, W1h, W1l, 2048, 512, P1, 4096);
        // LSTM1 finish: + Xc addend (carries biases); h1 -> XH[:,1024:], X2[:,1024:2048]
        k_finish<<<256, blk, 0, stream>>>(P1, 4096, 4, Xcf + (size_t)t * 4096, nullptr, nullptr,
                                          c1, XHh + 1024, 2048, X2h + 1024, 3072, nullptr, nullptr);
        // ah = h1_new @ (Wahh+Wahl)^T, N-tile 32, K-split 4
        k_gp2<<<dim3(32, 4), blk, 0, stream>>>(XHh + 1024, 2048, Wahh, Wahl, 1024, 256, PAH, 1024);
        k_score<<<dim3(8, 64), blk, 0, stream>>>(PAH, bah, wa, ba, PattBf, amask, SC);
        k_attsum<<<dim3(4, 64), blk, 0, stream>>>(SC, encbf, X2h);
        // cell2 gates: [att|h1|h2] @ (W2h+W2l)^T (4096x3072), N-tile 32, K-split 4, 2-pass
        k_gp2<<<dim3(128, 4), blk, 0, stream>>>(X2h, 3072, W2h, W2l, 3072, 768, P2, 4096);
        // LSTM2 finish: h2 -> XH[:,0:], X2[:,2048:], outputs, Xout
        k_finish<<<256, blk, 0, stream>>>(P2, 4096, 4, nullptr, bih2, bhh2,
                                          c2, XHh, 2048, X2h + 2048, 3072,
                                          outputs + (size_t)t * 1024, Xouth + (size_t)t * 1024);
    }

    // ofe = outputs @ Woe^T + boe (bf16 out, single-pass Woe; overlays dead Xaug region)
    k_gemm3<1, 1, 0, true><<<dim3(8, 11), blk, 0, stream>>>(
        Xouth, nullptr, 1024, Woebf, nullptr, 1024, boe, nullptr, OFEbf, 1024, 1344, 1024);
    k_nce_bf<<<dim3(21, 64), blk, 0, stream>>>(OFEbf, AFEbf, eosw, nce);
}

// Round 17
// 1532.860 us; speedup vs baseline: 1.4612x; 1.0173x over previous
//
#include <hip/hip_runtime.h>
#include <cmath>

typedef unsigned short u16;
typedef __attribute__((ext_vector_type(8))) short short8;
typedef __attribute__((ext_vector_type(4))) float floatx4;
typedef __attribute__((address_space(3))) unsigned int lds_u32;
typedef const __attribute__((address_space(1))) unsigned int glob_u32;

__device__ __forceinline__ u16 f2bf(float f) {
    unsigned u = __float_as_uint(f);
    unsigned r = u + 0x7fffu + ((u >> 16) & 1u);
    return (u16)(r >> 16);
}
__device__ __forceinline__ float bf2f(u16 h) { return __uint_as_float(((unsigned)h) << 16); }
__device__ __forceinline__ void split2(float x, u16& hi, u16& lo) {
    hi = f2bf(x);
    lo = f2bf(x - bf2f(hi));
}
__device__ __forceinline__ float sigm(float x) {
    x = fminf(fmaxf(x, -30.f), 30.f);
    return 1.0f / (1.0f + __expf(-x));
}
__device__ __forceinline__ float ftanh(float x) {
    x = fminf(fmaxf(x, -15.f), 15.f);
    float e = __expf(2.f * x);
    return (e - 1.f) / (e + 1.f);
}
__device__ __forceinline__ void gload16(const void* g, void* l) {
    __builtin_amdgcn_global_load_lds((glob_u32*)g, (lds_u32*)l, 16, 0, 0);
}

// ---------------- f32 -> bf16 (single) ----------------
__global__ __launch_bounds__(256) void k_cvt(const float* __restrict__ s, u16* __restrict__ d, int n4) {
    int i = blockIdx.x * 256 + threadIdx.x;
    int stride = gridDim.x * 256;
    for (; i < n4; i += stride) {
        float4 v = ((const float4*)s)[i];
        ushort4 o;
        o.x = f2bf(v.x); o.y = f2bf(v.y); o.z = f2bf(v.z); o.w = f2bf(v.w);
        ((ushort4*)d)[i] = o;
    }
}

// ---------------- f32 -> (hi, lo) bf16 planes ----------------
__global__ __launch_bounds__(256) void k_splitp(const float* __restrict__ s, u16* __restrict__ hi,
                                                u16* __restrict__ lo, int n4) {
    int i = blockIdx.x * 256 + threadIdx.x;
    int stride = gridDim.x * 256;
    for (; i < n4; i += stride) {
        float4 v = ((const float4*)s)[i];
        ushort4 h, l;
        split2(v.x, h.x, l.x); split2(v.y, h.y, l.y);
        split2(v.z, h.z, l.z); split2(v.w, h.w, l.w);
        ((ushort4*)hi)[i] = h;
        ((ushort4*)lo)[i] = l;
    }
}

// ---------------- weight concat builders (hi/lo planes) ----------------
// W1cat (4096 x 2048): [Wih1[:, :1024] | Whh1]
__global__ __launch_bounds__(256) void k_build_w1cat(const float* __restrict__ Wih1, const float* __restrict__ Whh1,
                                                     u16* __restrict__ dh, u16* __restrict__ dl) {
    int row = blockIdx.x;
    int c = threadIdx.x * 8;
    const float* src = (c < 1024) ? (Wih1 + (size_t)row * 3072 + c) : (Whh1 + (size_t)row * 1024 + (c - 1024));
    short8 h, l;
#pragma unroll
    for (int j = 0; j < 8; ++j) { u16 hh, ll; split2(src[j], hh, ll); h[j] = (short)hh; l[j] = (short)ll; }
    *(short8*)(dh + (size_t)row * 2048 + c) = h;
    *(short8*)(dl + (size_t)row * 2048 + c) = l;
}

// Wcat2 (4096 x 3072): [Wih2 | Whh2]   (384 threads)
__global__ __launch_bounds__(384) void k_build_wcat2(const float* __restrict__ Wih2, const float* __restrict__ Whh2,
                                                     u16* __restrict__ dh, u16* __restrict__ dl) {
    int row = blockIdx.x;
    int c = threadIdx.x * 8;
    const float* src = (c < 2048) ? (Wih2 + (size_t)row * 2048 + c) : (Whh2 + (size_t)row * 1024 + (c - 2048));
    short8 h, l;
#pragma unroll
    for (int j = 0; j < 8; ++j) { u16 hh, ll; split2(src[j], hh, ll); h[j] = (short)hh; l[j] = (short)ll; }
    *(short8*)(dh + (size_t)row * 3072 + c) = h;
    *(short8*)(dl + (size_t)row * 3072 + c) = l;
}

// Wx1 (4096 x 2048) = Wih1[:, 1024:3072]
__global__ __launch_bounds__(256) void k_build_wx1(const float* __restrict__ Wih1, u16* __restrict__ dh,
                                                   u16* __restrict__ dl) {
    int row = blockIdx.x;
    int c = threadIdx.x * 8;
    const float* src = Wih1 + (size_t)row * 3072 + 1024 + c;
    short8 h, l;
#pragma unroll
    for (int j = 0; j < 8; ++j) { u16 hh, ll; split2(src[j], hh, ll); h[j] = (short)hh; l[j] = (short)ll; }
    *(short8*)(dh + (size_t)row * 2048 + c) = h;
    *(short8*)(dl + (size_t)row * 2048 + c) = l;
}

// Xaug (1344 x 2048): [gv | x_t] single bf16
__global__ __launch_bounds__(256) void k_build_xaug(const float* __restrict__ enc, const int* __restrict__ obj,
                                                    const float* __restrict__ bos_w, u16* __restrict__ dh) {
    int b = blockIdx.x, t = blockIdx.y, tid = threadIdx.x;
    const float* gv = enc + (size_t)b * 129 * 1024;
    const float* xr;
    if (t == 0) xr = bos_w;
    else {
        int idx = obj[b * 20 + (t - 1)];
        idx = min(max(idx, 0), 127);
        xr = enc + ((size_t)b * 129 + 1 + idx) * 1024;
    }
    size_t rowoff = ((size_t)b * 21 + t) * 2048;
    float4 v0 = *(const float4*)(gv + tid * 4);
    float4 v1 = *(const float4*)(xr + tid * 4);
    ushort4 h0, h1;
    h0.x = f2bf(v0.x); h0.y = f2bf(v0.y); h0.z = f2bf(v0.z); h0.w = f2bf(v0.w);
    h1.x = f2bf(v1.x); h1.y = f2bf(v1.y); h1.z = f2bf(v1.z); h1.w = f2bf(v1.w);
    *(ushort4*)(dh + rowoff + tid * 4) = h0;
    *(ushort4*)(dh + rowoff + 1024 + tid * 4) = h1;
}

// ---------------- MFMA GEMM: C = A @ W^T + b1 + b2, split-precision passes ----------------
template <int APASS, int BPASS, int AREMAP, bool BF16OUT>
__global__ __launch_bounds__(256)
void k_gemm3(const u16* __restrict__ Ah, const u16* __restrict__ Al, int lda,
             const u16* __restrict__ Wh, const u16* __restrict__ Wl, int ldw,
             const float* __restrict__ b1, const float* __restrict__ b2,
             void* __restrict__ Cout, int ldc, int Mrows, int K) {
    constexpr int NP = APASS + BPASS;
    __shared__ char lds[2][NP][8192];
    const int tid = threadIdx.x;
    const int lane = tid & 63;
    const int lr = lane & 15, lk = lane >> 4;
    const int m0 = blockIdx.y * 128, n0 = blockIdx.x * 128;
    const int wid = tid >> 6;
    const int wr = wid >> 1, wc = wid & 1;
    const int wbyte = (tid & 192) * 16;

    floatx4 acc[4][4] = {};
    const int nt = K >> 5;

    auto stage = [&](int bb, int kt) {
        int k0 = kt * 32;
#pragma unroll
        for (int i = 0; i < 2; ++i) {
            int p = i * 256 + tid;
            int s = p ^ ((p >> 2) & 3);
            int row = s >> 2, kc = s & 3;
            size_t aoff;
            int gm = m0 + row;
            if (AREMAP == 1) aoff = (((size_t)(gm >> 7)) * 129 + 1 + (gm & 127)) * 1024 + k0 + kc * 8;
            else {
                int cm = gm < Mrows ? gm : Mrows - 1;
                aoff = (size_t)cm * lda + k0 + kc * 8;
            }
            gload16(Ah + aoff, &lds[bb][0][i * 4096 + wbyte]);
            if constexpr (APASS == 2) gload16(Al + aoff, &lds[bb][1][i * 4096 + wbyte]);
            size_t woff = (size_t)(n0 + row) * ldw + k0 + kc * 8;
            gload16(Wh + woff, &lds[bb][APASS][i * 4096 + wbyte]);
            if constexpr (BPASS == 2) gload16(Wl + woff, &lds[bb][APASS + 1][i * 4096 + wbyte]);
        }
    };

    stage(0, 0);
    __syncthreads();
    for (int t = 0; t < nt; ++t) {
        int bb = t & 1;
        if (t + 1 < nt) stage(bb ^ 1, t + 1);
        short8 ah_[4], al_[4], bh_[4], bl_[4];
#pragma unroll
        for (int mi = 0; mi < 4; ++mi) {
            int row = wr * 64 + mi * 16 + lr;
            int slot = (row * 4 + (lk ^ (row & 3))) * 16;
            ah_[mi] = *(const short8*)&lds[bb][0][slot];
            if constexpr (APASS == 2) al_[mi] = *(const short8*)&lds[bb][1][slot];
        }
#pragma unroll
        for (int ni = 0; ni < 4; ++ni) {
            int row = wc * 64 + ni * 16 + lr;
            int slot = (row * 4 + (lk ^ (row & 3))) * 16;
            bh_[ni] = *(const short8*)&lds[bb][APASS][slot];
            if constexpr (BPASS == 2) bl_[ni] = *(const short8*)&lds[bb][APASS + 1][slot];
        }
#pragma unroll
        for (int mi = 0; mi < 4; ++mi)
#pragma unroll
            for (int ni = 0; ni < 4; ++ni) {
                acc[mi][ni] = __builtin_amdgcn_mfma_f32_16x16x32_bf16(ah_[mi], bh_[ni], acc[mi][ni], 0, 0, 0);
                if constexpr (BPASS == 2)
                    acc[mi][ni] = __builtin_amdgcn_mfma_f32_16x16x32_bf16(ah_[mi], bl_[ni], acc[mi][ni], 0, 0, 0);
                if constexpr (APASS == 2)
                    acc[mi][ni] = __builtin_amdgcn_mfma_f32_16x16x32_bf16(al_[mi], bh_[ni], acc[mi][ni], 0, 0, 0);
            }
        __syncthreads();
    }
#pragma unroll
    for (int mi = 0; mi < 4; ++mi) {
#pragma unroll
        for (int r = 0; r < 4; ++r) {
            int gm = m0 + wr * 64 + mi * 16 + lk * 4 + r;
            if (AREMAP == 0 && gm >= Mrows) continue;
#pragma unroll
            for (int ni = 0; ni < 4; ++ni) {
                int gn = n0 + wc * 64 + ni * 16 + lr;
                float v = acc[mi][ni][r];
                if (b1) v += b1[gn];
                if (b2) v += b2[gn];
                if (BF16OUT) ((u16*)Cout)[(size_t)gm * ldc + gn] = f2bf(v);
                else ((float*)Cout)[(size_t)gm * ldc + gn] = v;
            }
        }
    }
}

// ---------------- skinny 2-pass GEMM, N-tile 32: P[kp] = X(64 x Klen) @ (Wh+Wl)^T(32 rows) ----------------
__global__ __launch_bounds__(256)
void k_gp2(const u16* __restrict__ Xh, int ldx,
           const u16* __restrict__ Wh, const u16* __restrict__ Wl, int ldw,
           int Klen, float* __restrict__ P, int Ntot) {
    __shared__ char lds[2][8192];  // [Xh 4096 | Wh 2048 | Wl 2048]
    const int tid = threadIdx.x, wid = tid >> 6, lane = tid & 63;
    const int lr = lane & 15, lk = lane >> 4;
    const int n0 = blockIdx.x * 32;
    const int koff = blockIdx.y * Klen;
    floatx4 acc[2] = {};
    const int nt = Klen >> 5;

    const int sX = tid ^ ((tid >> 2) & 3);
    const size_t xoff = (size_t)(sX >> 2) * ldx + (sX & 3) * 8 + koff;
    const int xdst = (tid & 192) * 16;
    const int pw = tid & 127;
    const int sW = pw ^ ((pw >> 2) & 3);
    const size_t woff = (size_t)(n0 + (sW >> 2)) * ldw + (sW & 3) * 8 + koff;
    const u16* Wsrc = (tid < 128) ? Wh : Wl;
    const int wdst = 4096 + (wid >> 1) * 2048 + (wid & 1) * 1024;

    auto stage = [&](int bb, int kt) {
        int k0 = kt * 32;
        gload16(Xh + xoff + k0, &lds[bb][xdst]);
        gload16(Wsrc + woff + k0, &lds[bb][wdst]);
    };

    stage(0, 0);
    __syncthreads();
    for (int t = 0; t < nt; ++t) {
        int bb = t & 1;
        if (t + 1 < nt) stage(bb ^ 1, t + 1);
        int arow = wid * 16 + lr;
        short8 xh = *(const short8*)&lds[bb][(arow * 4 + (lk ^ (arow & 3))) * 16];
#pragma unroll
        for (int ni = 0; ni < 2; ++ni) {
            int r = ni * 16 + lr;
            int slot = (r * 4 + (lk ^ (r & 3))) * 16;
            short8 wh = *(const short8*)&lds[bb][4096 + slot];
            short8 wl = *(const short8*)&lds[bb][6144 + slot];
            acc[ni] = __builtin_amdgcn_mfma_f32_16x16x32_bf16(xh, wh, acc[ni], 0, 0, 0);
            acc[ni] = __builtin_amdgcn_mfma_f32_16x16x32_bf16(xh, wl, acc[ni], 0, 0, 0);
        }
        __syncthreads();
    }
    float* Pb = P + (size_t)blockIdx.y * 64 * Ntot;
#pragma unroll
    for (int ni = 0; ni < 2; ++ni)
#pragma unroll
        for (int r = 0; r < 4; ++r) {
            int b = wid * 16 + lk * 4 + r;
            Pb[(size_t)b * Ntot + n0 + ni * 16 + lr] = acc[ni][r];
        }
}

// ---------------- reduce nP partials + LSTM cell (single-bf16 state outputs) ----------------
__global__ __launch_bounds__(256)
void k_finish(const float* __restrict__ P, int Ntot, int nP, const float* __restrict__ xcf,
              const float* __restrict__ b1, const float* __restrict__ b2,
              float* __restrict__ cst,
              u16* __restrict__ w1, int w1s, u16* __restrict__ w2, int w2s,
              float* __restrict__ outf, u16* __restrict__ oh) {
    int idx = blockIdx.x * 256 + threadIdx.x;  // b*1024 + d
    int b = idx >> 10, d = idx & 1023;
    float g[4];
#pragma unroll
    for (int q = 0; q < 4; ++q) {
        int n = q * 1024 + d;
        float s = 0.f;
        for (int p = 0; p < nP; ++p) s += P[((size_t)p * 64 + b) * Ntot + n];
        if (xcf) s += xcf[(size_t)b * 21 * 4096 + n];
        if (b1) s += b1[n];
        if (b2) s += b2[n];
        g[q] = s;
    }
    float cp = cst[idx];
    float cn = sigm(g[1]) * cp + sigm(g[0]) * ftanh(g[2]);
    float hn = sigm(g[3]) * ftanh(cn);
    cst[idx] = cn;
    u16 hh = f2bf(hn);
    w1[b * w1s + d] = hh;
    w2[b * w2s + d] = hh;
    if (outf) outf[(size_t)b * 21 * 1024 + d] = hn;
    if (oh) oh[(size_t)b * 21 * 1024 + d] = hh;
}

// ---------------- score: wa . tanh(p_att + ah) + ba, mask (bf16 p_att; ah from 4 partials) ----------------
__global__ __launch_bounds__(256)
void k_score(const float* __restrict__ PAH, const float* __restrict__ bah,
             const float* __restrict__ wa, const float* __restrict__ ba,
             const u16* __restrict__ Patt, const int* __restrict__ amask, float* __restrict__ SC) {
    int mc = blockIdx.x, b = blockIdx.y, tid = threadIdx.x;
    __shared__ float sah[1024], swa[1024];
    {
        int d = tid * 4;
        *(float4*)&swa[d] = *(const float4*)(wa + d);
        float4 s;
        float* sp = &s.x;
#pragma unroll
        for (int j = 0; j < 4; ++j) {
            float acc = bah[d + j];
#pragma unroll
            for (int p = 0; p < 4; ++p) acc += PAH[((size_t)p * 64 + b) * 1024 + d + j];
            sp[j] = acc;
        }
        *(float4*)&sah[d] = s;
    }
    __syncthreads();
    int wv = tid >> 6, lane = tid & 63;
    float bav = ba[0];
    for (int j = 0; j < 4; ++j) {
        int m = mc * 16 + wv * 4 + j;
        const u16* pr = Patt + ((size_t)(b * 128 + m)) * 1024;
        float part = 0.f;
#pragma unroll
        for (int c = 0; c < 4; ++c) {
            int d = c * 256 + lane * 4;
            ushort4 p4 = *(const ushort4*)(pr + d);
            float4 a4 = *(const float4*)&sah[d];
            float4 w4 = *(const float4*)&swa[d];
            part += ftanh(bf2f(p4.x) + a4.x) * w4.x + ftanh(bf2f(p4.y) + a4.y) * w4.y +
                    ftanh(bf2f(p4.z) + a4.z) * w4.z + ftanh(bf2f(p4.w) + a4.w) * w4.w;
        }
#pragma unroll
        for (int off = 32; off; off >>= 1) part += __shfl_down(part, off, 64);
        if (lane == 0) {
            float sc = part + bav;
            if (amask[b * 129 + 1 + m] == 0) sc = -1e9f;
            SC[b * 128 + m] = sc;
        }
    }
}

// ---------------- softmax + weighted feature sum (bf16 enc view, 129-row pitch) -> X2 att slot ----------------
__global__ __launch_bounds__(256)
void k_attsum(const float* __restrict__ SC, const u16* __restrict__ encbf,
              u16* __restrict__ X2h) {
    int dc = blockIdx.x, b = blockIdx.y, tid = threadIdx.x;
    __shared__ float salpha[128];
    __shared__ float sred[8];
    float sv = (tid < 128) ? SC[b * 128 + tid] : -1e30f;
    float mx = sv;
#pragma unroll
    for (int off = 32; off; off >>= 1) mx = fmaxf(mx, __shfl_down(mx, off, 64));
    if ((tid & 63) == 0) sred[tid >> 6] = mx;
    __syncthreads();
    float gmx = fmaxf(fmaxf(sred[0], sred[1]), fmaxf(sred[2], sred[3]));
    float ev = (tid < 128) ? __expf(sv - gmx) : 0.f;
    float s = ev;
#pragma unroll
    for (int off = 32; off; off >>= 1) s += __shfl_down(s, off, 64);
    if ((tid & 63) == 0) sred[4 + (tid >> 6)] = s;
    __syncthreads();
    float gsum = sred[4] + sred[5] + sred[6] + sred[7];
    if (tid < 128) salpha[tid] = ev / gsum;
    __syncthreads();
    int d = dc * 256 + tid;
    const u16* base = encbf + ((size_t)b * 129 + 1) * 1024 + d;
    float acc = 0.f;
#pragma unroll 8
    for (int m = 0; m < 128; ++m) acc += salpha[m] * bf2f(base[(size_t)m * 1024]);
    X2h[b * 3072 + d] = f2bf(acc);
}

// ---------------- nce_logit[b,l,j] = ofe[b,l,:] . afe[b,j,:]  (bf16 OFE/AFE, f32 eos) ----------------
__global__ __launch_bounds__(256)
void k_nce_bf(const u16* __restrict__ OFE, const u16* __restrict__ AFE,
              const float* __restrict__ eos_w, float* __restrict__ nce) {
    int l = blockIdx.x, b = blockIdx.y;
    __shared__ u16 sofe[1024];
    int tid = threadIdx.x;
    *(ushort4*)&sofe[tid * 4] = *(const ushort4*)(OFE + ((size_t)b * 21 + l) * 1024 + tid * 4);
    __syncthreads();
    int w = tid >> 6, lane = tid & 63;
    float* outp = nce + ((size_t)b * 21 + l) * 129;
    for (int j = w; j < 129; j += 4) {
        float part = 0.f;
        if (j == 0) {
#pragma unroll
            for (int c = 0; c < 4; ++c) {
                int d = c * 256 + lane * 4;
                float4 a4 = *(const float4*)(eos_w + d);
                ushort4 o4 = *(const ushort4*)&sofe[d];
                part += a4.x * bf2f(o4.x) + a4.y * bf2f(o4.y) + a4.z * bf2f(o4.z) + a4.w * bf2f(o4.w);
            }
        } else {
            const u16* ar = AFE + ((size_t)b * 128 + (j - 1)) * 1024;
#pragma unroll
            for (int c = 0; c < 4; ++c) {
                int d = c * 256 + lane * 4;
                ushort4 a4 = *(const ushort4*)(ar + d);
                ushort4 o4 = *(const ushort4*)&sofe[d];
                part += bf2f(a4.x) * bf2f(o4.x) + bf2f(a4.y) * bf2f(o4.y) +
                        bf2f(a4.z) * bf2f(o4.z) + bf2f(a4.w) * bf2f(o4.w);
            }
        }
#pragma unroll
        for (int off = 32; off; off >>= 1) part += __shfl_down(part, off, 64);
        if (lane == 0) outp[j] = part;
    }
}

extern "C" void kernel_launch(void* const* d_in, const int* in_sizes, int n_in,
                              void* d_out, int out_size, void* d_ws, size_t ws_size,
                              hipStream_t stream) {
    const float* enc  = (const float*)d_in[0];
    const int*   obj  = (const int*)d_in[1];
    const int*   amask= (const int*)d_in[2];
    const float* bosw = (const float*)d_in[3];
    const float* eosw = (const float*)d_in[4];
    const float* Wp   = (const float*)d_in[5];
    const float* bp   = (const float*)d_in[6];
    const float* Wih1 = (const float*)d_in[7];
    const float* Whh1 = (const float*)d_in[8];
    const float* bih1 = (const float*)d_in[9];
    const float* bhh1 = (const float*)d_in[10];
    const float* Wih2 = (const float*)d_in[11];
    const float* Whh2 = (const float*)d_in[12];
    const float* bih2 = (const float*)d_in[13];
    const float* bhh2 = (const float*)d_in[14];
    const float* Wah  = (const float*)d_in[15];
    const float* bah  = (const float*)d_in[16];
    const float* wa   = (const float*)d_in[17];
    const float* ba   = (const float*)d_in[18];
    const float* Wae  = (const float*)d_in[19];
    const float* bae  = (const float*)d_in[20];
    const float* Woe  = (const float*)d_in[21];
    const float* boe  = (const float*)d_in[22];

    float* outputs = (float*)d_out;                    // (64,21,1024)
    float* nce     = outputs + (size_t)64 * 21 * 1024; // (64,21,129)

    char* wp = (char*)d_ws;
    auto alloc = [&](size_t bytes) -> char* { char* p = wp; wp += (bytes + 255) & ~(size_t)255; return p; };
    u16* encbf  = (u16*)alloc((size_t)64 * 129 * 1024 * 2);   // live through whole run (attsum reads it)
    u16* Wpbf   = (u16*)alloc((size_t)1024 * 1024 * 2);
    u16* Xaugh  = (u16*)alloc((size_t)1344 * 2048 * 2);       // pre-scan only -> OFEbf overlay
    u16* W1h    = (u16*)alloc((size_t)4096 * 2048 * 2);
    u16* W1l    = (u16*)alloc((size_t)4096 * 2048 * 2);
    u16* W2h    = (u16*)alloc((size_t)4096 * 3072 * 2);
    u16* W2l    = (u16*)alloc((size_t)4096 * 3072 * 2);
    u16* Wahh   = (u16*)alloc((size_t)1024 * 1024 * 2);
    u16* Wahl   = (u16*)alloc((size_t)1024 * 1024 * 2);
    u16* Waebf  = (u16*)alloc((size_t)1024 * 1024 * 2);
    u16* Woebf  = (u16*)alloc((size_t)1024 * 1024 * 2);
    // region1: Wx1 hi/lo (33.5MB); after Xc GEMM reused for AFEbf (16.8MB)
    char* region1 = alloc((size_t)2 * 4096 * 2048 * 2);
    u16* Wx1h = (u16*)region1;
    u16* Wx1l = (u16*)region1 + (size_t)4096 * 2048;
    u16* AFEbf = (u16*)region1;
    u16* PattBf  = (u16*)alloc((size_t)8192 * 1024 * 2);
    float* Xcf   = (float*)alloc((size_t)1344 * 4096 * 4);
    u16* Xouth   = (u16*)alloc((size_t)1344 * 1024 * 2);
    float* P2    = (float*)alloc((size_t)4 * 64 * 4096 * 4);
    float* P1    = (float*)alloc((size_t)4 * 64 * 4096 * 4);
    float* PAH   = (float*)alloc((size_t)4 * 64 * 1024 * 4);
    u16* XHh     = (u16*)alloc((size_t)64 * 2048 * 2);   // [h2 | h1]
    u16* X2h     = (u16*)alloc((size_t)64 * 3072 * 2);   // [att | h1 | h2]
    float* c1    = (float*)alloc((size_t)64 * 1024 * 4);
    float* c2    = (float*)alloc((size_t)64 * 1024 * 4);
    float* SC    = (float*)alloc((size_t)64 * 128 * 4);
    // OFEbf overlays Xaugh (Xaug dead after Xc GEMM)
    u16* OFEbf = Xaugh;

    dim3 blk(256);
    // prep
    k_cvt<<<2048, blk, 0, stream>>>(enc, encbf, 64 * 129 * 1024 / 4);
    k_cvt<<<1024, blk, 0, stream>>>(Wp, Wpbf, 1024 * 1024 / 4);
    k_cvt<<<1024, blk, 0, stream>>>(Wae, Waebf, 1024 * 1024 / 4);
    k_cvt<<<1024, blk, 0, stream>>>(Woe, Woebf, 1024 * 1024 / 4);
    k_splitp<<<1024, blk, 0, stream>>>(Wah, Wahh, Wahl, 1024 * 1024 / 4);
    k_build_wx1<<<4096, blk, 0, stream>>>(Wih1, Wx1h, Wx1l);
    k_build_w1cat<<<4096, blk, 0, stream>>>(Wih1, Whh1, W1h, W1l);
    k_build_wcat2<<<4096, dim3(384), 0, stream>>>(Wih2, Whh2, W2h, W2l);
    k_build_xaug<<<dim3(64, 21), blk, 0, stream>>>(enc, obj, bosw, Xaugh);

    // p_att (bf16 out, single-pass Wp): att_feats @ Wp^T + bp
    k_gemm3<1, 1, 1, true><<<dim3(8, 64), blk, 0, stream>>>(
        encbf, nullptr, 0, Wpbf, nullptr, 1024, bp, nullptr, PattBf, 1024, 8192, 1024);
    // Xc (A single, W split, f32 out): Xaug @ Wx1^T + bih1 + bhh1   (reads region1 as Wx1)
    k_gemm3<1, 2, 0, false><<<dim3(32, 11), blk, 0, stream>>>(
        Xaugh, nullptr, 2048, Wx1h, Wx1l, 2048, bih1, bhh1, Xcf, 4096, 1344, 2048);
    // afe (bf16 out, single-pass Wae): att_feats @ Wae^T + bae   (writes region1 as AFEbf)
    k_gemm3<1, 1, 1, true><<<dim3(8, 64), blk, 0, stream>>>(
        encbf, nullptr, 0, Waebf, nullptr, 1024, bae, nullptr, AFEbf, 1024, 8192, 1024);

    // scan-state init
    hipMemsetAsync(XHh, 0, (size_t)64 * 2048 * 2, stream);
    hipMemsetAsync(X2h, 0, (size_t)64 * 3072 * 2, stream);
    hipMemsetAsync(c1, 0, (size_t)64 * 1024 * 4, stream);
    hipMemsetAsync(c2, 0, (size_t)64 * 1024 * 4, stream);

    for (int t = 0; t < 21; ++t) {
        // cell1 gates: [h2|h1] @ (W1h+W1l)^T (4096x2048), N-tile 32, K-split 4, 2-pass
        k_gp2<<<dim3(128, 4), blk, 0, stream>>>(XHh, 2048, W1h, W1l, 2048, 512, P1, 4096);
        // LSTM1 finish: + Xc addend (carries biases); h1 -> XH[:,1024:], X2[:,1024:2048]
        k_finish<<<256, blk, 0, stream>>>(P1, 4096, 4, Xcf + (size_t)t * 4096, nullptr, nullptr,
                                          c1, XHh + 1024, 2048, X2h + 1024, 3072, nullptr, nullptr);
        // ah = h1_new @ (Wahh+Wahl)^T, N-tile 32, K-split 4
        k_gp2<<<dim3(32, 4), blk, 0, stream>>>(XHh + 1024, 2048, Wahh, Wahl, 1024, 256, PAH, 1024);
        k_score<<<dim3(8, 64), blk, 0, stream>>>(PAH, bah, wa, ba, PattBf, amask, SC);
        k_attsum<<<dim3(4, 64), blk, 0, stream>>>(SC, encbf, X2h);
        // cell2 gates: [att|h1|h2] @ (W2h+W2l)^T (4096x3072), N-tile 32, K-split 4, 2-pass
        k_gp2<<<dim3(128, 4), blk, 0, stream>>>(X2h, 3072, W2h, W2l, 3072, 768, P2, 4096);
        // LSTM2 finish: h2 -> XH[:,0:], X2[:,2048:], outputs, Xout
        k_finish<<<256, blk, 0, stream>>>(P2, 4096, 4, nullptr, bih2, bhh2,
                                          c2, XHh, 2048, X2h + 2048, 3072,
                                          outputs + (size_t)t * 1024, Xouth + (size_t)t * 1024);
    }

    // ofe = outputs @ Woe^T + boe (bf16 out, single-pass Woe; overlays dead Xaug region)
    k_gemm3<1, 1, 0, true><<<dim3(8, 11), blk, 0, stream>>>(
        Xouth, nullptr, 1024, Woebf, nullptr, 1024, boe, nullptr, OFEbf, 1024, 1344, 1024);
    k_nce_bf<<<dim3(21, 64), blk, 0, stream>>>(OFEbf, AFEbf, eosw, nce);
}